// Round 1
// 63.404 us; speedup vs baseline: 1.0797x; 1.0797x over previous
//
#include <hip/hip_runtime.h>

// Problem constants (B,S,H,E)=(64,512,768,8), HID=256
#define HH   768
#define SS   512
#define BB   64
#define EE   8
#define NE   512          // B*E rows
#define K3   2304         // 3*H
#define HID  256
#define NCH  16           // chunks per batch
#define CRW  32           // rows per chunk

typedef __attribute__((ext_vector_type(4))) float  f32x4;
typedef __attribute__((ext_vector_type(8))) short  s16x8;
typedef __attribute__((ext_vector_type(8))) unsigned short u16x8;
typedef __attribute__((ext_vector_type(4))) unsigned short u16x4;

__device__ __forceinline__ unsigned short f2bf(float x) {
  unsigned u = __float_as_uint(x);
  return (unsigned short)((u + 0x7fffu + ((u >> 16) & 1u)) >> 16);
}

// ---------------------------------------------------------------------------
// K1: per-(batch,chunk) partial sums over 32 rows, with prefix "captures" at
// event positions (entity starts, ends+1).  Extra blocks transpose+convert
// pW1/aW1/iW1 (2304x256 fp32) into wT (bf16, [768 n][2304 k]).
// ---------------------------------------------------------------------------
__global__ __launch_bounds__(192) void k_scan(
    const float* __restrict__ seq, const int* __restrict__ starts,
    const int* __restrict__ ends, const float* __restrict__ pW1,
    const float* __restrict__ aW1, const float* __restrict__ iW1,
    float* __restrict__ chunkSum, float* __restrict__ cap,
    unsigned short* __restrict__ wT)
{
  __shared__ float Ls[48 * 65];
  const int bx = blockIdx.x;
  const int t  = threadIdx.x;

  if (bx < BB * NCH) {
    // ---- scan block ----
    const int b = bx >> 4, c = bx & 15;
    int ev[16];
#pragma unroll
    for (int j = 0; j < 8; j++) {
      ev[j]     = starts[b * 8 + j];
      ev[8 + j] = ends[b * 8 + j] + 1;
    }
    // wave-uniform mask of rows in this chunk that need a capture store
    unsigned rowhit = 0;
#pragma unroll
    for (int j = 0; j < 16; j++) {
      const int d = ev[j] - c * CRW;
      if ((unsigned)d < 32u) rowhit |= (1u << d);
    }
    const float* base = seq + ((size_t)(b * SS + c * CRW)) * HH + t * 4;
    f32x4 run = {0.f, 0.f, 0.f, 0.f};
#pragma unroll 8
    for (int r = 0; r < CRW; r++) {
      const int s = c * CRW + r;
      if (rowhit & (1u << r)) {        // uniform (scalar) branch, rare
#pragma unroll
        for (int j = 0; j < 16; j++) {
          if (ev[j] == s)
            *(f32x4*)(cap + ((size_t)(b * 16 + j)) * HH + t * 4) = run;
        }
      }
      f32x4 v = *(const f32x4*)(base + (size_t)r * HH);
      run += v;
    }
    *(f32x4*)(chunkSum + ((size_t)(b * 16 + c)) * HH + t * 4) = run;
  } else {
    // ---- W1 transpose/convert block: 48(k) x 64(n) tile ----
    const int bi   = bx - BB * NCH;       // 0..575
    const int head = bi / 192;            // 0=p,1=a,2=i
    const int r    = bi % 192;
    const int kt = r >> 2, nt = r & 3;
    const int k0 = kt * 48, n0 = nt * 64;
    const float* W = (head == 0) ? pW1 : ((head == 1) ? aW1 : iW1);
#pragma unroll
    for (int p = 0; p < 4; p++) {
      const int row = (t >> 4) + p * 12;     // 0..47
      const int col = (t & 15) * 4;          // 0..60
      f32x4 v = *(const f32x4*)(W + (size_t)(k0 + row) * HID + n0 + col);
      Ls[row * 65 + col + 0] = v.x;
      Ls[row * 65 + col + 1] = v.y;
      Ls[row * 65 + col + 2] = v.z;
      Ls[row * 65 + col + 3] = v.w;
    }
    __syncthreads();
    const int n = t / 3, u = t % 3;          // n:0..63, u:0..2
#pragma unroll
    for (int j = 0; j < 2; j++) {
      const int kb = u * 16 + j * 8;         // 0..40 step 8
      u16x8 pk;
#pragma unroll
      for (int i = 0; i < 8; i++) pk[i] = f2bf(Ls[(kb + i) * 65 + n]);
      *(u16x8*)(wT + (size_t)(head * 256 + n0 + n) * K3 + k0 + kb) = pk;
    }
  }
}

// ---------------------------------------------------------------------------
// K2: build emb (512 x 2304) fp32 + bf16 from chunk sums and captures.
// ---------------------------------------------------------------------------
__global__ __launch_bounds__(192) void k_emb(
    const float* __restrict__ chunkSum, const float* __restrict__ cap,
    const int* __restrict__ starts, const int* __restrict__ ends,
    float* __restrict__ emb32, unsigned short* __restrict__ embB)
{
  const int bx = blockIdx.x;            // row = b*8+e
  const int t  = threadIdx.x;
  const int b = bx >> 3, e = bx & 7;
  const int s  = starts[b * 8 + e];
  const int en = ends[b * 8 + e];
  const int cs = s >> 5, ce = (en + 1) >> 5;   // both <= 15

  const float* csb = chunkSum + (size_t)(b * 16) * HH + t * 4;
  f32x4 acc = {0.f, 0.f, 0.f, 0.f};
  f32x4 baseS = {0.f, 0.f, 0.f, 0.f}, baseE = {0.f, 0.f, 0.f, 0.f};
#pragma unroll
  for (int c = 0; c < 16; c++) {
    if (c == cs) baseS = acc;
    if (c == ce) baseE = acc;
    acc += *(const f32x4*)(csb + (size_t)c * HH);
  }
  f32x4 capS = *(const f32x4*)(cap + (size_t)(b * 16 + e) * HH + t * 4);
  f32x4 capE = *(const f32x4*)(cap + (size_t)(b * 16 + 8 + e) * HH + t * 4);
  f32x4 Ps = baseS + capS;
  f32x4 Pe = baseE + capE;
  f32x4 Pt = acc;

  f32x4 zero = {0.f, 0.f, 0.f, 0.f};
  f32x4 left = zero;
  if (s > 0) left = Ps * (1.0f / (float)s);
  f32x4 span = (Pe - Ps) * (1.0f / (float)(en - s + 1));
  const int rc = SS - (en + 1);
  f32x4 right = zero;
  if (rc > 0) right = (Pt - Pe) * (1.0f / (float)rc);

  float* o = emb32 + (size_t)bx * K3 + t * 4;
  *(f32x4*)(o)        = left;
  *(f32x4*)(o + 768)  = span;
  *(f32x4*)(o + 1536) = right;

  unsigned short* ob = embB + (size_t)bx * K3 + t * 4;
  u16x4 p0, p1, p2;
#pragma unroll
  for (int i = 0; i < 4; i++) { p0[i] = f2bf(left[i]); p1[i] = f2bf(span[i]); p2[i] = f2bf(right[i]); }
  *(u16x4*)(ob)        = p0;
  *(u16x4*)(ob + 768)  = p1;
  *(u16x4*)(ob + 1536) = p2;
}

// ---------------------------------------------------------------------------
// K3: blocks 0..191  : bf16 MFMA GEMM  H1T[n][m] = sum_k wT[n][k]*emb[m][k]
//                      (p/a/i heads, N=768, M=512, K=2304, 32x64 tiles)
//     blocks 192..447: fp32 split-K GEMM for main head -> mainPart[8][512][256]
// Both paths: double-buffered LDS, reg-staged prefetch of K-tile kt+1 issued
// BEFORE the compute of kt; single barrier per K-step (T3-minimum pipeline).
// ---------------------------------------------------------------------------
__global__ __launch_bounds__(128) void k_gemm(
    const unsigned short* __restrict__ embB, const unsigned short* __restrict__ wT,
    const float* __restrict__ emb32, const float* __restrict__ mW1,
    float* __restrict__ H1T, float* __restrict__ mainPart)
{
  __shared__ __align__(16) char smem[27648];   // 2 x 13824 (MFMA) / 2 x 8192 (fp32)
  const int bx = blockIdx.x;
  const int t  = threadIdx.x;

  if (bx < 192) {
    // ---------------- MFMA path ----------------
    // per buffer: A [32][72] bf16 (4608 B) then B [64][72] bf16 (9216 B)
    const int mt = bx & 15, nt = bx >> 4;
    const int m0 = mt * 32, nG0 = nt * 64;
    const int l = t & 63, w = t >> 6;       // 2 waves, wave w owns n-half
    const int klane = l >> 4;               // 0..3
    const int lr = l & 15;
    f32x4 acc[2][2] = {};

    // staging addresses (constant per thread; k advances by immediate)
    const int am = t >> 2, ako = (t & 3) * 8;           // A: 32 x 64
    const unsigned short* gA = embB + (size_t)(m0 + am) * K3 + ako;
    const int aoff = am * 72 + ako;
    const unsigned short* gBp[4];
    int boff[4];
#pragma unroll
    for (int p = 0; p < 4; p++) {                        // B: 64 x 64
      const int ch = t + p * 128;
      const int bn = ch >> 3, bko = (ch & 7) * 8;
      gBp[p] = wT + (size_t)(nG0 + bn) * K3 + bko;
      boff[p] = bn * 72 + bko;
    }

    // prologue: stage kt=0 into buffer 0
    {
      u16x8 a0 = *(const u16x8*)(gA);
      u16x8 a1 = *(const u16x8*)(gA + 32);
      u16x8 b0 = *(const u16x8*)(gBp[0]);
      u16x8 b1 = *(const u16x8*)(gBp[1]);
      u16x8 b2 = *(const u16x8*)(gBp[2]);
      u16x8 b3 = *(const u16x8*)(gBp[3]);
      unsigned short* Ac = (unsigned short*)smem;
      unsigned short* Bc = Ac + 2304;        // 32*72 shorts
      *(u16x8*)(Ac + aoff)      = a0;
      *(u16x8*)(Ac + aoff + 32) = a1;
      *(u16x8*)(Bc + boff[0]) = b0;
      *(u16x8*)(Bc + boff[1]) = b1;
      *(u16x8*)(Bc + boff[2]) = b2;
      *(u16x8*)(Bc + boff[3]) = b3;
    }
    __syncthreads();

    int cur = 0;
    for (int kt = 0; kt < 36; kt++) {
      // issue next K-tile loads FIRST (latency hides under compute below)
      u16x8 nA0, nA1, nB0, nB1, nB2, nB3;
      const bool pre = (kt < 35);
      if (pre) {
        const int kn = (kt + 1) * 64;
        nA0 = *(const u16x8*)(gA + kn);
        nA1 = *(const u16x8*)(gA + kn + 32);
        nB0 = *(const u16x8*)(gBp[0] + kn);
        nB1 = *(const u16x8*)(gBp[1] + kn);
        nB2 = *(const u16x8*)(gBp[2] + kn);
        nB3 = *(const u16x8*)(gBp[3] + kn);
      }
      // compute from current buffer
      unsigned short* Ac = (unsigned short*)(smem + cur * 13824);
      unsigned short* Bc = Ac + 2304;
#pragma unroll
      for (int ks2 = 0; ks2 < 2; ks2++) {
        s16x8 aW[2], bE[2];
#pragma unroll
        for (int f = 0; f < 2; f++) {
          aW[f] = *(const s16x8*)(Bc + (w * 32 + f * 16 + lr) * 72 + ks2 * 32 + klane * 8);
          bE[f] = *(const s16x8*)(Ac + (f * 16 + lr) * 72 + ks2 * 32 + klane * 8);
        }
#pragma unroll
        for (int fn = 0; fn < 2; fn++)
#pragma unroll
          for (int fm = 0; fm < 2; fm++)
            acc[fn][fm] = __builtin_amdgcn_mfma_f32_16x16x32_bf16(
                aW[fn], bE[fm], acc[fn][fm], 0, 0, 0);
      }
      // write prefetched tile into the other buffer (no one reads it this iter)
      if (pre) {
        unsigned short* An = (unsigned short*)(smem + (cur ^ 1) * 13824);
        unsigned short* Bn = An + 2304;
        *(u16x8*)(An + aoff)      = nA0;
        *(u16x8*)(An + aoff + 32) = nA1;
        *(u16x8*)(Bn + boff[0]) = nB0;
        *(u16x8*)(Bn + boff[1]) = nB1;
        *(u16x8*)(Bn + boff[2]) = nB2;
        *(u16x8*)(Bn + boff[3]) = nB3;
      }
      __syncthreads();
      cur ^= 1;
    }
#pragma unroll
    for (int fn = 0; fn < 2; fn++)
#pragma unroll
      for (int fm = 0; fm < 2; fm++)
#pragma unroll
        for (int rg = 0; rg < 4; rg++) {
          const int n_l = nG0 + w * 32 + fn * 16 + klane * 4 + rg;
          const int m_l = m0 + fm * 16 + lr;
          H1T[(size_t)n_l * NE + m_l] = acc[fn][fm][rg];
        }
  } else {
    // ---------------- fp32 main path (split-K) ----------------
    // per buffer: A [16][64] f32 (4096 B) then B [16][64] f32 (4096 B)
    const int bi = bx - 192;
    const int mt = bi & 7, nt = (bi >> 3) & 3, ksi = bi >> 5;
    const int m0 = mt * 64, n0 = nt * 64, kc0 = ksi * 288;
    const int tx = t & 15, ty = t >> 4;   // micro-tile 8 rows x 4 cols
    float acc[8][4] = {};

    const int sm = t & 63, skq = t >> 6;               // A: 64 m x 2 kq
    const float* gA = emb32 + (size_t)(m0 + sm) * K3 + kc0 + skq * 8;
    const int skk = t >> 3, snb = t & 7;               // B: 16 k x 8 nb
    const float* gB = mW1 + (size_t)(kc0 + skk) * HID + n0 + snb * 8;

    // prologue: stage st=0 into buffer 0
    {
      f32x4 a0 = *(const f32x4*)(gA);
      f32x4 a1 = *(const f32x4*)(gA + 4);
      f32x4 b0 = *(const f32x4*)(gB);
      f32x4 b1 = *(const f32x4*)(gB + 4);
      float* Asf = (float*)smem;
      float* Bsf = Asf + 1024;
#pragma unroll
      for (int i = 0; i < 4; i++) {
        Asf[(skq * 8 + i) * 64 + sm]     = a0[i];
        Asf[(skq * 8 + 4 + i) * 64 + sm] = a1[i];
      }
      *(f32x4*)(Bsf + skk * 64 + snb * 8)     = b0;
      *(f32x4*)(Bsf + skk * 64 + snb * 8 + 4) = b1;
    }
    __syncthreads();

    int cur = 0;
    for (int st = 0; st < 18; st++) {
      f32x4 nA0, nA1, nB0, nB1;
      const bool pre = (st < 17);
      if (pre) {
        const int kn = (st + 1) * 16;
        nA0 = *(const f32x4*)(gA + kn);
        nA1 = *(const f32x4*)(gA + kn + 4);
        nB0 = *(const f32x4*)(gB + (size_t)kn * HID);
        nB1 = *(const f32x4*)(gB + (size_t)kn * HID + 4);
      }
      float* Asf = (float*)(smem + cur * 8192);
      float* Bsf = Asf + 1024;
#pragma unroll
      for (int kk = 0; kk < 16; kk++) {
        f32x4 a0 = *(const f32x4*)(Asf + kk * 64 + ty * 8);
        f32x4 a1 = *(const f32x4*)(Asf + kk * 64 + ty * 8 + 4);
        f32x4 b  = *(const f32x4*)(Bsf + kk * 64 + tx * 4);
#pragma unroll
        for (int i = 0; i < 4; i++)
#pragma unroll
          for (int j = 0; j < 4; j++) {
            acc[i][j]     = fmaf(a0[i], b[j], acc[i][j]);
            acc[4 + i][j] = fmaf(a1[i], b[j], acc[4 + i][j]);
          }
      }
      if (pre) {
        float* An = (float*)(smem + (cur ^ 1) * 8192);
        float* Bn = An + 1024;
#pragma unroll
        for (int i = 0; i < 4; i++) {
          An[(skq * 8 + i) * 64 + sm]     = nA0[i];
          An[(skq * 8 + 4 + i) * 64 + sm] = nA1[i];
        }
        *(f32x4*)(Bn + skk * 64 + snb * 8)     = nB0;
        *(f32x4*)(Bn + skk * 64 + snb * 8 + 4) = nB1;
      }
      __syncthreads();
      cur ^= 1;
    }
#pragma unroll
    for (int i = 0; i < 8; i++) {
      f32x4 stv = {acc[i][0], acc[i][1], acc[i][2], acc[i][3]};
      *(f32x4*)(mainPart + ((size_t)ksi * NE + m0 + ty * 8 + i) * HID + n0 + tx * 4) = stv;
    }
  }
}

// ---------------------------------------------------------------------------
// K4: per entity-row epilogue: reduce split-K, biases, ReLU, layer-2 dots,
// softmax/argmax, sigmoids, padded select, write outputs.
// ---------------------------------------------------------------------------
__global__ __launch_bounds__(64) void k_head(
    const float* __restrict__ H1T, const float* __restrict__ mainPart,
    const float* __restrict__ mb1, const float* __restrict__ mW2, const float* __restrict__ mb2,
    const float* __restrict__ pb1, const float* __restrict__ pW2, const float* __restrict__ pb2,
    const float* __restrict__ ab1, const float* __restrict__ aW2, const float* __restrict__ ab2,
    const float* __restrict__ ib1, const float* __restrict__ iW2, const float* __restrict__ ib2,
    float* __restrict__ out)
{
  const int m = blockIdx.x;
  const int l = threadIdx.x;
  float am0 = 0.f, am1 = 0.f, am2 = 0.f;
  float ap[6]  = {};
  float aa[12] = {};
  float ai[4]  = {};

#pragma unroll
  for (int q = 0; q < 4; q++) {
    const int n = q * 64 + l;
    float h = 0.f;
#pragma unroll
    for (int ks = 0; ks < 8; ks++)
      h += mainPart[((size_t)ks * NE + m) * HID + n];
    h += mb1[n];
    h = h > 0.f ? h : 0.f;
    am0 = fmaf(h, mW2[n * 3 + 0], am0);
    am1 = fmaf(h, mW2[n * 3 + 1], am1);
    am2 = fmaf(h, mW2[n * 3 + 2], am2);

    float hp = H1T[(size_t)n * NE + m] + pb1[n];
    hp = hp > 0.f ? hp : 0.f;
#pragma unroll
    for (int o = 0; o < 6; o++) ap[o] = fmaf(hp, pW2[n * 6 + o], ap[o]);

    float ha = H1T[(size_t)(256 + n) * NE + m] + ab1[n];
    ha = ha > 0.f ? ha : 0.f;
#pragma unroll
    for (int o = 0; o < 12; o++) aa[o] = fmaf(ha, aW2[n * 12 + o], aa[o]);

    float hi = H1T[(size_t)(512 + n) * NE + m] + ib1[n];
    hi = hi > 0.f ? hi : 0.f;
#pragma unroll
    for (int o = 0; o < 4; o++) ai[o] = fmaf(hi, iW2[n * 4 + o], ai[o]);
  }

#pragma unroll
  for (int d = 1; d < 64; d <<= 1) {
    am0 += __shfl_xor(am0, d);
    am1 += __shfl_xor(am1, d);
    am2 += __shfl_xor(am2, d);
#pragma unroll
    for (int o = 0; o < 6; o++)  ap[o] += __shfl_xor(ap[o], d);
#pragma unroll
    for (int o = 0; o < 12; o++) aa[o] += __shfl_xor(aa[o], d);
#pragma unroll
    for (int o = 0; o < 4; o++)  ai[o] += __shfl_xor(ai[o], d);
  }

  if (l == 0) {
    const float l0 = am0 + mb2[0], l1 = am1 + mb2[1], l2 = am2 + mb2[2];
    const float mx = fmaxf(l0, fmaxf(l1, l2));
    const float e0 = expf(l0 - mx), e1 = expf(l1 - mx), e2 = expf(l2 - mx);
    const float inv = 1.0f / (e0 + e1 + e2);
    const float p0 = e0 * inv, p1 = e1 * inv, p2 = e2 * inv;
    int pred = 0;
    float pb = p0;
    if (p1 > pb) { pb = p1; pred = 1; }
    if (p2 > pb) { pb = p2; pred = 2; }

    out[m * 3 + 0] = l0;
    out[m * 3 + 1] = l1;
    out[m * 3 + 2] = l2;
    out[1536 + m * 3 + 0] = p0;
    out[1536 + m * 3 + 1] = p1;
    out[1536 + m * 3 + 2] = p2;

    float f[22];
#pragma unroll
    for (int j = 0; j < 22; j++) f[j] = 0.f;
    if (pred == 0) {
#pragma unroll
      for (int j = 0; j < 6; j++)  f[j]      = 1.0f / (1.0f + expf(-(ap[j] + pb2[j])));
    } else if (pred == 1) {
#pragma unroll
      for (int j = 0; j < 12; j++) f[6 + j]  = 1.0f / (1.0f + expf(-(aa[j] + ab2[j])));
    } else {
#pragma unroll
      for (int j = 0; j < 4; j++)  f[18 + j] = 1.0f / (1.0f + expf(-(ai[j] + ib2[j])));
    }
#pragma unroll
    for (int j = 0; j < 22; j++) out[3072 + m * 22 + j] = f[j];
  }
}

// ---------------------------------------------------------------------------
extern "C" void kernel_launch(void* const* d_in, const int* in_sizes, int n_in,
                              void* d_out, int out_size, void* d_ws, size_t ws_size,
                              hipStream_t stream)
{
  const float* seq    = (const float*)d_in[0];
  const int*   starts = (const int*)d_in[1];
  const int*   ends   = (const int*)d_in[2];
  const float* mW1 = (const float*)d_in[3];
  const float* mb1 = (const float*)d_in[4];
  const float* mW2 = (const float*)d_in[5];
  const float* mb2 = (const float*)d_in[6];
  const float* pW1 = (const float*)d_in[7];
  const float* pb1 = (const float*)d_in[8];
  const float* pW2 = (const float*)d_in[9];
  const float* pb2 = (const float*)d_in[10];
  const float* aW1 = (const float*)d_in[11];
  const float* ab1 = (const float*)d_in[12];
  const float* aW2 = (const float*)d_in[13];
  const float* ab2 = (const float*)d_in[14];
  const float* iW1 = (const float*)d_in[15];
  const float* ib1 = (const float*)d_in[16];
  const float* iW2 = (const float*)d_in[17];
  const float* ib2 = (const float*)d_in[18];

  char* ws = (char*)d_ws;
  float*          chunkSum = (float*)(ws);                       // 64*16*768*4 = 3,145,728
  float*          cap      = (float*)(ws + 3145728);             // 3,145,728
  float*          emb32    = (float*)(ws + 6291456);             // 512*2304*4 = 4,718,592
  unsigned short* embB     = (unsigned short*)(ws + 11010048);   // 512*2304*2 = 2,359,296
  unsigned short* wT       = (unsigned short*)(ws + 13369344);   // 768*2304*2 = 3,538,944
  float*          H1T      = (float*)(ws + 16908288);            // 768*512*4  = 1,572,864
  float*          mainPart = (float*)(ws + 18481152);            // 8*512*256*4= 4,194,304
  // total ws use: 22,675,456 bytes

  k_scan<<<dim3(1600), dim3(192), 0, stream>>>(seq, starts, ends, pW1, aW1, iW1,
                                               chunkSum, cap, wT);
  k_emb<<<dim3(512), dim3(192), 0, stream>>>(chunkSum, cap, starts, ends, emb32, embB);
  k_gemm<<<dim3(448), dim3(128), 0, stream>>>(embB, wT, emb32, mW1, H1T, mainPart);
  k_head<<<dim3(512), dim3(64), 0, stream>>>(H1T, mainPart,
                                             mb1, mW2, mb2, pb1, pW2, pb2,
                                             ab1, aW2, ab2, ib1, iW2, ib2,
                                             (float*)d_out);
}

// Round 2
// 60.048 us; speedup vs baseline: 1.1401x; 1.0559x over previous
//
#include <hip/hip_runtime.h>

// Problem constants (B,S,H,E)=(64,512,768,8), HID=256
#define HH   768
#define SS   512
#define BB   64
#define EE   8
#define NE   512          // B*E rows
#define K3   2304         // 3*H
#define HID  256
#define NCH  16           // chunks per batch
#define CRW  32           // rows per chunk

typedef __attribute__((ext_vector_type(4))) float  f32x4;
typedef __attribute__((ext_vector_type(8))) short  s16x8;
typedef __attribute__((ext_vector_type(8))) unsigned short u16x8;
typedef __attribute__((ext_vector_type(4))) unsigned short u16x4;

__device__ __forceinline__ unsigned short f2bf(float x) {
  unsigned u = __float_as_uint(x);
  return (unsigned short)((u + 0x7fffu + ((u >> 16) & 1u)) >> 16);
}
__device__ __forceinline__ float bf2f(unsigned short h) {
  return __uint_as_float((unsigned)h << 16);
}

// ---------------------------------------------------------------------------
// K1: blocks 0..1023: per-(batch,chunk) partial sums over 32 rows with prefix
//     captures at event positions.
//     blocks 1024..1791: transpose+convert W1 matrices to bf16 [n][k]:
//     heads 0..2 = pW1/aW1/iW1 -> wT; head 3 = mW1 -> wTmH (hi) + wTmL (lo).
// ---------------------------------------------------------------------------
__global__ __launch_bounds__(192) void k_scan(
    const float* __restrict__ seq, const int* __restrict__ starts,
    const int* __restrict__ ends, const float* __restrict__ pW1,
    const float* __restrict__ aW1, const float* __restrict__ iW1,
    const float* __restrict__ mW1,
    float* __restrict__ chunkSum, float* __restrict__ cap,
    unsigned short* __restrict__ wT, unsigned short* __restrict__ wTmH,
    unsigned short* __restrict__ wTmL)
{
  __shared__ float Ls[48 * 65];
  const int bx = blockIdx.x;
  const int t  = threadIdx.x;

  if (bx < BB * NCH) {
    // ---- scan block ----
    const int b = bx >> 4, c = bx & 15;
    int ev[16];
#pragma unroll
    for (int j = 0; j < 8; j++) {
      ev[j]     = starts[b * 8 + j];
      ev[8 + j] = ends[b * 8 + j] + 1;
    }
    // wave-uniform mask of rows in this chunk that need a capture store
    unsigned rowhit = 0;
#pragma unroll
    for (int j = 0; j < 16; j++) {
      const int d = ev[j] - c * CRW;
      if ((unsigned)d < 32u) rowhit |= (1u << d);
    }
    const float* base = seq + ((size_t)(b * SS + c * CRW)) * HH + t * 4;
    f32x4 run = {0.f, 0.f, 0.f, 0.f};
#pragma unroll 8
    for (int r = 0; r < CRW; r++) {
      const int s = c * CRW + r;
      if (rowhit & (1u << r)) {        // uniform (scalar) branch, rare
#pragma unroll
        for (int j = 0; j < 16; j++) {
          if (ev[j] == s)
            *(f32x4*)(cap + ((size_t)(b * 16 + j)) * HH + t * 4) = run;
        }
      }
      f32x4 v = *(const f32x4*)(base + (size_t)r * HH);
      run += v;
    }
    *(f32x4*)(chunkSum + ((size_t)(b * 16 + c)) * HH + t * 4) = run;
  } else {
    // ---- W1 transpose/convert block: 48(k) x 64(n) tile ----
    const int bi   = bx - BB * NCH;       // 0..767
    const int head = bi / 192;            // 0=p,1=a,2=i,3=main
    const int r    = bi % 192;
    const int kt = r >> 2, nt = r & 3;
    const int k0 = kt * 48, n0 = nt * 64;
    const float* W = (head == 0) ? pW1 : ((head == 1) ? aW1 :
                     ((head == 2) ? iW1 : mW1));
#pragma unroll
    for (int p = 0; p < 4; p++) {
      const int row = (t >> 4) + p * 12;     // 0..47
      const int col = (t & 15) * 4;          // 0..60
      f32x4 v = *(const f32x4*)(W + (size_t)(k0 + row) * HID + n0 + col);
      Ls[row * 65 + col + 0] = v.x;
      Ls[row * 65 + col + 1] = v.y;
      Ls[row * 65 + col + 2] = v.z;
      Ls[row * 65 + col + 3] = v.w;
    }
    __syncthreads();
    const int n = t / 3, u = t % 3;          // n:0..63, u:0..2
    if (head < 3) {
#pragma unroll
      for (int j = 0; j < 2; j++) {
        const int kb = u * 16 + j * 8;       // 0..40 step 8
        u16x8 pk;
#pragma unroll
        for (int i = 0; i < 8; i++) pk[i] = f2bf(Ls[(kb + i) * 65 + n]);
        *(u16x8*)(wT + (size_t)(head * 256 + n0 + n) * K3 + k0 + kb) = pk;
      }
    } else {
#pragma unroll
      for (int j = 0; j < 2; j++) {
        const int kb = u * 16 + j * 8;
        u16x8 ph, pl;
#pragma unroll
        for (int i = 0; i < 8; i++) {
          const float x = Ls[(kb + i) * 65 + n];
          const unsigned short h = f2bf(x);
          ph[i] = h;
          pl[i] = f2bf(x - bf2f(h));         // exact residual (Sterbenz)
        }
        *(u16x8*)(wTmH + (size_t)(n0 + n) * K3 + k0 + kb) = ph;
        *(u16x8*)(wTmL + (size_t)(n0 + n) * K3 + k0 + kb) = pl;
      }
    }
  }
}

// ---------------------------------------------------------------------------
// K2: build emb (512 x 2304) as bf16 hi (embB) + bf16 residual (embLo).
// ---------------------------------------------------------------------------
__global__ __launch_bounds__(192) void k_emb(
    const float* __restrict__ chunkSum, const float* __restrict__ cap,
    const int* __restrict__ starts, const int* __restrict__ ends,
    unsigned short* __restrict__ embB, unsigned short* __restrict__ embLo)
{
  const int bx = blockIdx.x;            // row = b*8+e
  const int t  = threadIdx.x;
  const int b = bx >> 3, e = bx & 7;
  const int s  = starts[b * 8 + e];
  const int en = ends[b * 8 + e];
  const int cs = s >> 5, ce = (en + 1) >> 5;   // both <= 15

  const float* csb = chunkSum + (size_t)(b * 16) * HH + t * 4;
  f32x4 acc = {0.f, 0.f, 0.f, 0.f};
  f32x4 baseS = {0.f, 0.f, 0.f, 0.f}, baseE = {0.f, 0.f, 0.f, 0.f};
#pragma unroll
  for (int c = 0; c < 16; c++) {
    if (c == cs) baseS = acc;
    if (c == ce) baseE = acc;
    acc += *(const f32x4*)(csb + (size_t)c * HH);
  }
  f32x4 capS = *(const f32x4*)(cap + (size_t)(b * 16 + e) * HH + t * 4);
  f32x4 capE = *(const f32x4*)(cap + (size_t)(b * 16 + 8 + e) * HH + t * 4);
  f32x4 Ps = baseS + capS;
  f32x4 Pe = baseE + capE;
  f32x4 Pt = acc;

  f32x4 zero = {0.f, 0.f, 0.f, 0.f};
  f32x4 left = zero;
  if (s > 0) left = Ps * (1.0f / (float)s);
  f32x4 span = (Pe - Ps) * (1.0f / (float)(en - s + 1));
  const int rc = SS - (en + 1);
  f32x4 right = zero;
  if (rc > 0) right = (Pt - Pe) * (1.0f / (float)rc);

  unsigned short* ob = embB  + (size_t)bx * K3 + t * 4;
  unsigned short* ol = embLo + (size_t)bx * K3 + t * 4;
  u16x4 p0, p1, p2, q0, q1, q2;
#pragma unroll
  for (int i = 0; i < 4; i++) {
    p0[i] = f2bf(left[i]);  q0[i] = f2bf(left[i]  - bf2f(p0[i]));
    p1[i] = f2bf(span[i]);  q1[i] = f2bf(span[i]  - bf2f(p1[i]));
    p2[i] = f2bf(right[i]); q2[i] = f2bf(right[i] - bf2f(p2[i]));
  }
  *(u16x4*)(ob)        = p0;
  *(u16x4*)(ob + 768)  = p1;
  *(u16x4*)(ob + 1536) = p2;
  *(u16x4*)(ol)        = q0;
  *(u16x4*)(ol + 768)  = q1;
  *(u16x4*)(ol + 1536) = q2;
}

// ---------------------------------------------------------------------------
// K3: uniform bf16 MFMA GEMM, 384 blocks, 32x64 output tiles, K=2304.
//   blocks 0..191  : pai heads:  Hall[m][n] (n 0..767), A=embB, B=wT
//   blocks 192..447: main head bf16x2, 3 passes (hi*hi, hi*lo, lo*hi) into
//                    mainPart[pass][m][n] (n 0..255); k_head sums the passes.
// Double-buffered LDS + reg-staged prefetch (1-deep), single barrier/K-step.
// Epilogue: LDS transpose so global output is m-major (coalesced in k_head).
// ---------------------------------------------------------------------------
__global__ __launch_bounds__(128) void k_gemm(
    const unsigned short* __restrict__ embB, const unsigned short* __restrict__ embLo,
    const unsigned short* __restrict__ wT, const unsigned short* __restrict__ wTmH,
    const unsigned short* __restrict__ wTmL,
    float* __restrict__ Hall, float* __restrict__ mainPart)
{
  __shared__ __align__(16) char smem[27648];   // 2 x (A 32x72 + B 64x72) bf16
  const int bx = blockIdx.x;
  const int t  = threadIdx.x;

  const unsigned short* Abase;
  const unsigned short* Bbase;
  float* outp;
  int ncols, m0, nG0;
  if (bx < 192) {
    const int mt = bx & 15, nt = bx >> 4;      // nt 0..11
    m0 = mt * 32; nG0 = nt * 64;
    Abase = embB; Bbase = wT; outp = Hall; ncols = 768;
  } else {
    const int bi = bx - 192;
    const int pass = bi >> 6;                  // 0..2
    const int mt = bi & 15, nt = (bi >> 4) & 3;
    m0 = mt * 32; nG0 = nt * 64;
    Abase = (pass == 2) ? embLo : embB;
    Bbase = (pass == 1) ? wTmL : wTmH;
    outp = mainPart + (size_t)pass * NE * HID; ncols = HID;
  }

  const int l = t & 63, w = t >> 6;       // 2 waves, wave w owns n-half
  const int klane = l >> 4;               // 0..3
  const int lr = l & 15;
  f32x4 acc[2][2] = {};

  // staging addresses (constant per thread; k advances by immediate)
  const int am = t >> 2, ako = (t & 3) * 8;           // A: 32 x 64
  const unsigned short* gA = Abase + (size_t)(m0 + am) * K3 + ako;
  const int aoff = am * 72 + ako;
  const unsigned short* gBp[4];
  int boff[4];
#pragma unroll
  for (int p = 0; p < 4; p++) {                        // B: 64 x 64
    const int ch = t + p * 128;
    const int bn = ch >> 3, bko = (ch & 7) * 8;
    gBp[p] = Bbase + (size_t)(nG0 + bn) * K3 + bko;
    boff[p] = bn * 72 + bko;
  }

  // prologue: stage kt=0 into buffer 0
  {
    u16x8 a0 = *(const u16x8*)(gA);
    u16x8 a1 = *(const u16x8*)(gA + 32);
    u16x8 b0 = *(const u16x8*)(gBp[0]);
    u16x8 b1 = *(const u16x8*)(gBp[1]);
    u16x8 b2 = *(const u16x8*)(gBp[2]);
    u16x8 b3 = *(const u16x8*)(gBp[3]);
    unsigned short* Ac = (unsigned short*)smem;
    unsigned short* Bc = Ac + 2304;        // 32*72 shorts
    *(u16x8*)(Ac + aoff)      = a0;
    *(u16x8*)(Ac + aoff + 32) = a1;
    *(u16x8*)(Bc + boff[0]) = b0;
    *(u16x8*)(Bc + boff[1]) = b1;
    *(u16x8*)(Bc + boff[2]) = b2;
    *(u16x8*)(Bc + boff[3]) = b3;
  }
  __syncthreads();

  int cur = 0;
  for (int kt = 0; kt < 36; kt++) {
    // issue next K-tile loads FIRST (latency hides under compute below)
    u16x8 nA0, nA1, nB0, nB1, nB2, nB3;
    const bool pre = (kt < 35);
    if (pre) {
      const int kn = (kt + 1) * 64;
      nA0 = *(const u16x8*)(gA + kn);
      nA1 = *(const u16x8*)(gA + kn + 32);
      nB0 = *(const u16x8*)(gBp[0] + kn);
      nB1 = *(const u16x8*)(gBp[1] + kn);
      nB2 = *(const u16x8*)(gBp[2] + kn);
      nB3 = *(const u16x8*)(gBp[3] + kn);
    }
    // compute from current buffer
    unsigned short* Ac = (unsigned short*)(smem + cur * 13824);
    unsigned short* Bc = Ac + 2304;
#pragma unroll
    for (int ks2 = 0; ks2 < 2; ks2++) {
      s16x8 aW[2], bE[2];
#pragma unroll
      for (int f = 0; f < 2; f++) {
        aW[f] = *(const s16x8*)(Bc + (w * 32 + f * 16 + lr) * 72 + ks2 * 32 + klane * 8);
        bE[f] = *(const s16x8*)(Ac + (f * 16 + lr) * 72 + ks2 * 32 + klane * 8);
      }
#pragma unroll
      for (int fn = 0; fn < 2; fn++)
#pragma unroll
        for (int fm = 0; fm < 2; fm++)
          acc[fn][fm] = __builtin_amdgcn_mfma_f32_16x16x32_bf16(
              aW[fn], bE[fm], acc[fn][fm], 0, 0, 0);
    }
    // write prefetched tile into the other buffer
    if (pre) {
      unsigned short* An = (unsigned short*)(smem + (cur ^ 1) * 13824);
      unsigned short* Bn = An + 2304;
      *(u16x8*)(An + aoff)      = nA0;
      *(u16x8*)(An + aoff + 32) = nA1;
      *(u16x8*)(Bn + boff[0]) = nB0;
      *(u16x8*)(Bn + boff[1]) = nB1;
      *(u16x8*)(Bn + boff[2]) = nB2;
      *(u16x8*)(Bn + boff[3]) = nB3;
    }
    __syncthreads();
    cur ^= 1;
  }

  // ---- epilogue: transpose via LDS, store m-major (coalesced for k_head) ----
  float* Lt = (float*)smem;               // [32][68] f32
#pragma unroll
  for (int fn = 0; fn < 2; fn++)
#pragma unroll
    for (int fm = 0; fm < 2; fm++) {
      const int nl = w * 32 + fn * 16 + klane * 4;
      const int ml = fm * 16 + lr;
      *(f32x4*)(Lt + ml * 68 + nl) = acc[fn][fm];
    }
  __syncthreads();
  const int row = t >> 2, cb = (t & 3) * 16;
  float* dst = outp + (size_t)(m0 + row) * ncols + nG0 + cb;
  const float* src = Lt + row * 68 + cb;
#pragma unroll
  for (int i = 0; i < 4; i++)
    *(f32x4*)(dst + i * 4) = *(const f32x4*)(src + i * 4);
}

// ---------------------------------------------------------------------------
// K4: per entity-row epilogue — all loads now coalesced (m-major layouts).
// ---------------------------------------------------------------------------
__global__ __launch_bounds__(64) void k_head(
    const float* __restrict__ Hall, const float* __restrict__ mainPart,
    const float* __restrict__ mb1, const float* __restrict__ mW2, const float* __restrict__ mb2,
    const float* __restrict__ pb1, const float* __restrict__ pW2, const float* __restrict__ pb2,
    const float* __restrict__ ab1, const float* __restrict__ aW2, const float* __restrict__ ab2,
    const float* __restrict__ ib1, const float* __restrict__ iW2, const float* __restrict__ ib2,
    float* __restrict__ out)
{
  const int m = blockIdx.x;
  const int l = threadIdx.x;
  float am0 = 0.f, am1 = 0.f, am2 = 0.f;
  float ap[6]  = {};
  float aa[12] = {};
  float ai[4]  = {};

#pragma unroll
  for (int q = 0; q < 4; q++) {
    const int n = q * 64 + l;
    float h = mainPart[((size_t)0 * NE + m) * HID + n]
            + mainPart[((size_t)1 * NE + m) * HID + n]
            + mainPart[((size_t)2 * NE + m) * HID + n]
            + mb1[n];
    h = h > 0.f ? h : 0.f;
    am0 = fmaf(h, mW2[n * 3 + 0], am0);
    am1 = fmaf(h, mW2[n * 3 + 1], am1);
    am2 = fmaf(h, mW2[n * 3 + 2], am2);

    float hp = Hall[(size_t)m * 768 + n] + pb1[n];
    hp = hp > 0.f ? hp : 0.f;
#pragma unroll
    for (int o = 0; o < 6; o++) ap[o] = fmaf(hp, pW2[n * 6 + o], ap[o]);

    float ha = Hall[(size_t)m * 768 + 256 + n] + ab1[n];
    ha = ha > 0.f ? ha : 0.f;
#pragma unroll
    for (int o = 0; o < 12; o++) aa[o] = fmaf(ha, aW2[n * 12 + o], aa[o]);

    float hv = Hall[(size_t)m * 768 + 512 + n] + ib1[n];
    hv = hv > 0.f ? hv : 0.f;
#pragma unroll
    for (int o = 0; o < 4; o++) ai[o] = fmaf(hv, iW2[n * 4 + o], ai[o]);
  }

#pragma unroll
  for (int d = 1; d < 64; d <<= 1) {
    am0 += __shfl_xor(am0, d);
    am1 += __shfl_xor(am1, d);
    am2 += __shfl_xor(am2, d);
#pragma unroll
    for (int o = 0; o < 6; o++)  ap[o] += __shfl_xor(ap[o], d);
#pragma unroll
    for (int o = 0; o < 12; o++) aa[o] += __shfl_xor(aa[o], d);
#pragma unroll
    for (int o = 0; o < 4; o++)  ai[o] += __shfl_xor(ai[o], d);
  }

  if (l == 0) {
    const float l0 = am0 + mb2[0], l1 = am1 + mb2[1], l2 = am2 + mb2[2];
    const float mx = fmaxf(l0, fmaxf(l1, l2));
    const float e0 = expf(l0 - mx), e1 = expf(l1 - mx), e2 = expf(l2 - mx);
    const float inv = 1.0f / (e0 + e1 + e2);
    const float p0 = e0 * inv, p1 = e1 * inv, p2 = e2 * inv;
    int pred = 0;
    float pb = p0;
    if (p1 > pb) { pb = p1; pred = 1; }
    if (p2 > pb) { pb = p2; pred = 2; }

    out[m * 3 + 0] = l0;
    out[m * 3 + 1] = l1;
    out[m * 3 + 2] = l2;
    out[1536 + m * 3 + 0] = p0;
    out[1536 + m * 3 + 1] = p1;
    out[1536 + m * 3 + 2] = p2;

    float f[22];
#pragma unroll
    for (int j = 0; j < 22; j++) f[j] = 0.f;
    if (pred == 0) {
#pragma unroll
      for (int j = 0; j < 6; j++)  f[j]      = 1.0f / (1.0f + expf(-(ap[j] + pb2[j])));
    } else if (pred == 1) {
#pragma unroll
      for (int j = 0; j < 12; j++) f[6 + j]  = 1.0f / (1.0f + expf(-(aa[j] + ab2[j])));
    } else {
#pragma unroll
      for (int j = 0; j < 4; j++)  f[18 + j] = 1.0f / (1.0f + expf(-(ai[j] + ib2[j])));
    }
#pragma unroll
    for (int j = 0; j < 22; j++) out[3072 + m * 22 + j] = f[j];
  }
}

// ---------------------------------------------------------------------------
extern "C" void kernel_launch(void* const* d_in, const int* in_sizes, int n_in,
                              void* d_out, int out_size, void* d_ws, size_t ws_size,
                              hipStream_t stream)
{
  const float* seq    = (const float*)d_in[0];
  const int*   starts = (const int*)d_in[1];
  const int*   ends   = (const int*)d_in[2];
  const float* mW1 = (const float*)d_in[3];
  const float* mb1 = (const float*)d_in[4];
  const float* mW2 = (const float*)d_in[5];
  const float* mb2 = (const float*)d_in[6];
  const float* pW1 = (const float*)d_in[7];
  const float* pb1 = (const float*)d_in[8];
  const float* pW2 = (const float*)d_in[9];
  const float* pb2 = (const float*)d_in[10];
  const float* aW1 = (const float*)d_in[11];
  const float* ab1 = (const float*)d_in[12];
  const float* aW2 = (const float*)d_in[13];
  const float* ab2 = (const float*)d_in[14];
  const float* iW1 = (const float*)d_in[15];
  const float* ib1 = (const float*)d_in[16];
  const float* iW2 = (const float*)d_in[17];
  const float* ib2 = (const float*)d_in[18];

  char* ws = (char*)d_ws;
  float*          chunkSum = (float*)(ws);                       // 3,145,728
  float*          cap      = (float*)(ws + 3145728);             // 3,145,728
  unsigned short* embB     = (unsigned short*)(ws + 6291456);    // 2,359,296
  unsigned short* embLo    = (unsigned short*)(ws + 8650752);    // 2,359,296
  unsigned short* wT       = (unsigned short*)(ws + 11010048);   // 3,538,944
  unsigned short* wTmH     = (unsigned short*)(ws + 14548992);   // 1,179,648
  unsigned short* wTmL     = (unsigned short*)(ws + 15728640);   // 1,179,648
  float*          Hall     = (float*)(ws + 16908288);            // 512*768*4 = 1,572,864
  float*          mainPart = (float*)(ws + 18481152);            // 3*512*256*4 = 1,572,864
  // total ws use: 20,054,016 bytes

  k_scan<<<dim3(1792), dim3(192), 0, stream>>>(seq, starts, ends, pW1, aW1, iW1, mW1,
                                               chunkSum, cap, wT, wTmH, wTmL);
  k_emb<<<dim3(512), dim3(192), 0, stream>>>(chunkSum, cap, starts, ends, embB, embLo);
  k_gemm<<<dim3(384), dim3(128), 0, stream>>>(embB, embLo, wT, wTmH, wTmL, Hall, mainPart);
  k_head<<<dim3(512), dim3(64), 0, stream>>>(Hall, mainPart,
                                             mb1, mW2, mb2, pb1, pW2, pb2,
                                             ab1, aW2, ab2, ib1, iW2, ib2,
                                             (float*)d_out);
}

// Round 4
// 52.905 us; speedup vs baseline: 1.2940x; 1.1350x over previous
//
#include <hip/hip_runtime.h>

// Problem constants (B,S,H,E)=(64,512,768,8), HID=256
#define HH   768
#define SS   512
#define BB   64
#define EE   8
#define NE   512          // B*E rows
#define K3   2304         // 3*H
#define HID  256
#define NCH  16           // chunks per batch
#define CRW  32           // rows per chunk

typedef __attribute__((ext_vector_type(4))) float  f32x4;
typedef __attribute__((ext_vector_type(8))) short  s16x8;
typedef __attribute__((ext_vector_type(8))) unsigned short u16x8;
typedef __attribute__((ext_vector_type(4))) unsigned short u16x4;

__device__ __forceinline__ unsigned short f2bf(float x) {
  unsigned u = __float_as_uint(x);
  return (unsigned short)((u + 0x7fffu + ((u >> 16) & 1u)) >> 16);
}
__device__ __forceinline__ float bf2f(unsigned short h) {
  return __uint_as_float((unsigned)h << 16);
}

// ---------------------------------------------------------------------------
// K1: blocks 0..1023: per-(batch,chunk) partial sums over 32 rows with prefix
//     captures at event positions.
//     blocks 1024..1791: transpose+convert W1 matrices to bf16 [n][k]:
//     heads 0..2 = pW1/aW1/iW1 -> wT; head 3 = mW1 -> wTmH (hi) + wTmL (lo).
// ---------------------------------------------------------------------------
__global__ __launch_bounds__(192) void k_scan(
    const float* __restrict__ seq, const int* __restrict__ starts,
    const int* __restrict__ ends, const float* __restrict__ pW1,
    const float* __restrict__ aW1, const float* __restrict__ iW1,
    const float* __restrict__ mW1,
    float* __restrict__ chunkSum, float* __restrict__ cap,
    unsigned short* __restrict__ wT, unsigned short* __restrict__ wTmH,
    unsigned short* __restrict__ wTmL)
{
  __shared__ float Ls[48 * 65];
  const int bx = blockIdx.x;
  const int t  = threadIdx.x;

  if (bx < BB * NCH) {
    // ---- scan block ----
    const int b = bx >> 4, c = bx & 15;
    int ev[16];
#pragma unroll
    for (int j = 0; j < 8; j++) {
      ev[j]     = starts[b * 8 + j];
      ev[8 + j] = ends[b * 8 + j] + 1;
    }
    // wave-uniform mask of rows in this chunk that need a capture store
    unsigned rowhit = 0;
#pragma unroll
    for (int j = 0; j < 16; j++) {
      const int d = ev[j] - c * CRW;
      if ((unsigned)d < 32u) rowhit |= (1u << d);
    }
    const float* base = seq + ((size_t)(b * SS + c * CRW)) * HH + t * 4;
    f32x4 run = {0.f, 0.f, 0.f, 0.f};
#pragma unroll 8
    for (int r = 0; r < CRW; r++) {
      const int s = c * CRW + r;
      if (rowhit & (1u << r)) {        // uniform (scalar) branch, rare
#pragma unroll
        for (int j = 0; j < 16; j++) {
          if (ev[j] == s)
            *(f32x4*)(cap + ((size_t)(b * 16 + j)) * HH + t * 4) = run;
        }
      }
      f32x4 v = *(const f32x4*)(base + (size_t)r * HH);
      run += v;
    }
    *(f32x4*)(chunkSum + ((size_t)(b * 16 + c)) * HH + t * 4) = run;
  } else {
    // ---- W1 transpose/convert block: 48(k) x 64(n) tile ----
    const int bi   = bx - BB * NCH;       // 0..767
    const int head = bi / 192;            // 0=p,1=a,2=i,3=main
    const int r    = bi % 192;
    const int kt = r >> 2, nt = r & 3;
    const int k0 = kt * 48, n0 = nt * 64;
    const float* W = (head == 0) ? pW1 : ((head == 1) ? aW1 :
                     ((head == 2) ? iW1 : mW1));
#pragma unroll
    for (int p = 0; p < 4; p++) {
      const int row = (t >> 4) + p * 12;     // 0..47
      const int col = (t & 15) * 4;          // 0..60
      f32x4 v = *(const f32x4*)(W + (size_t)(k0 + row) * HID + n0 + col);
      Ls[row * 65 + col + 0] = v.x;
      Ls[row * 65 + col + 1] = v.y;
      Ls[row * 65 + col + 2] = v.z;
      Ls[row * 65 + col + 3] = v.w;
    }
    __syncthreads();
    const int n = t / 3, u = t % 3;          // n:0..63, u:0..2
    if (head < 3) {
#pragma unroll
      for (int j = 0; j < 2; j++) {
        const int kb = u * 16 + j * 8;       // 0..40 step 8
        u16x8 pk;
#pragma unroll
        for (int i = 0; i < 8; i++) pk[i] = f2bf(Ls[(kb + i) * 65 + n]);
        *(u16x8*)(wT + (size_t)(head * 256 + n0 + n) * K3 + k0 + kb) = pk;
      }
    } else {
#pragma unroll
      for (int j = 0; j < 2; j++) {
        const int kb = u * 16 + j * 8;
        u16x8 ph, pl;
#pragma unroll
        for (int i = 0; i < 8; i++) {
          const float x = Ls[(kb + i) * 65 + n];
          const unsigned short h = f2bf(x);
          ph[i] = h;
          pl[i] = f2bf(x - bf2f(h));         // exact residual
        }
        *(u16x8*)(wTmH + (size_t)(n0 + n) * K3 + k0 + kb) = ph;
        *(u16x8*)(wTmL + (size_t)(n0 + n) * K3 + k0 + kb) = pl;
      }
    }
  }
}

// ---------------------------------------------------------------------------
// K2: build emb (512 x 2304) as bf16 hi (embB) + bf16 residual (embLo).
// ---------------------------------------------------------------------------
__global__ __launch_bounds__(192) void k_emb(
    const float* __restrict__ chunkSum, const float* __restrict__ cap,
    const int* __restrict__ starts, const int* __restrict__ ends,
    unsigned short* __restrict__ embB, unsigned short* __restrict__ embLo)
{
  const int bx = blockIdx.x;            // row = b*8+e
  const int t  = threadIdx.x;
  const int b = bx >> 3, e = bx & 7;
  const int s  = starts[b * 8 + e];
  const int en = ends[b * 8 + e];
  const int cs = s >> 5, ce = (en + 1) >> 5;   // both <= 15

  const float* csb = chunkSum + (size_t)(b * 16) * HH + t * 4;
  f32x4 acc = {0.f, 0.f, 0.f, 0.f};
  f32x4 baseS = {0.f, 0.f, 0.f, 0.f}, baseE = {0.f, 0.f, 0.f, 0.f};
#pragma unroll
  for (int c = 0; c < 16; c++) {
    if (c == cs) baseS = acc;
    if (c == ce) baseE = acc;
    acc += *(const f32x4*)(csb + (size_t)c * HH);
  }
  f32x4 capS = *(const f32x4*)(cap + (size_t)(b * 16 + e) * HH + t * 4);
  f32x4 capE = *(const f32x4*)(cap + (size_t)(b * 16 + 8 + e) * HH + t * 4);
  f32x4 Ps = baseS + capS;
  f32x4 Pe = baseE + capE;
  f32x4 Pt = acc;

  f32x4 zero = {0.f, 0.f, 0.f, 0.f};
  f32x4 left = zero;
  if (s > 0) left = Ps * (1.0f / (float)s);
  f32x4 span = (Pe - Ps) * (1.0f / (float)(en - s + 1));
  const int rc = SS - (en + 1);
  f32x4 right = zero;
  if (rc > 0) right = (Pt - Pe) * (1.0f / (float)rc);

  unsigned short* ob = embB  + (size_t)bx * K3 + t * 4;
  unsigned short* ol = embLo + (size_t)bx * K3 + t * 4;
  u16x4 p0, p1, p2, q0, q1, q2;
#pragma unroll
  for (int i = 0; i < 4; i++) {
    p0[i] = f2bf(left[i]);  q0[i] = f2bf(left[i]  - bf2f(p0[i]));
    p1[i] = f2bf(span[i]);  q1[i] = f2bf(span[i]  - bf2f(p1[i]));
    p2[i] = f2bf(right[i]); q2[i] = f2bf(right[i] - bf2f(p2[i]));
  }
  *(u16x4*)(ob)        = p0;
  *(u16x4*)(ob + 768)  = p1;
  *(u16x4*)(ob + 1536) = p2;
  *(u16x4*)(ol)        = q0;
  *(u16x4*)(ol + 768)  = q1;
  *(u16x4*)(ol + 1536) = q2;
}

// ---------------------------------------------------------------------------
// K3: uniform bf16 MFMA GEMM, 384 blocks, 32x64 output tiles, K=2304.
//   blocks 0..191  : pai heads:  Hall[m][n] (n 0..767), A=embB, B=wT
//   blocks 192..447: main head bf16x2, 3 passes into mainPart[pass][m][n].
// 2-deep modulo-scheduled pipeline: load T(kt+2)->regs, compute T(kt) from
// LDS, ds_write T(kt+1); one barrier per K-step.  Named register sets.
// (R3 bug: q-prefetch guard was kt<32, dropping tile 35 — fixed to kt<34.)
// ---------------------------------------------------------------------------
__global__ __launch_bounds__(128) void k_gemm(
    const unsigned short* __restrict__ embB, const unsigned short* __restrict__ embLo,
    const unsigned short* __restrict__ wT, const unsigned short* __restrict__ wTmH,
    const unsigned short* __restrict__ wTmL,
    float* __restrict__ Hall, float* __restrict__ mainPart)
{
  __shared__ __align__(16) char smem[27648];   // 2 x (A 32x72 + B 64x72) bf16
  const int bx = blockIdx.x;
  const int t  = threadIdx.x;

  const unsigned short* Abase;
  const unsigned short* Bbase;
  float* outp;
  int ncols, m0, nG0;
  if (bx < 192) {
    const int mt = bx & 15, nt = bx >> 4;      // nt 0..11
    m0 = mt * 32; nG0 = nt * 64;
    Abase = embB; Bbase = wT; outp = Hall; ncols = 768;
  } else {
    const int bi = bx - 192;
    const int pass = bi >> 6;                  // 0..2
    const int mt = bi & 15, nt = (bi >> 4) & 3;
    m0 = mt * 32; nG0 = nt * 64;
    Abase = (pass == 2) ? embLo : embB;
    Bbase = (pass == 1) ? wTmL : wTmH;
    outp = mainPart + (size_t)pass * NE * HID; ncols = HID;
  }

  const int l = t & 63, w = t >> 6;       // 2 waves, wave w owns n-half
  const int klane = l >> 4;               // 0..3
  const int lr = l & 15;
  f32x4 acc[2][2] = {};

  // staging addresses (constant per thread; k advances by immediate)
  const int am = t >> 2, ako = (t & 3) * 8;           // A: 32 x 64
  const unsigned short* gA = Abase + (size_t)(m0 + am) * K3 + ako;
  const int aoff = am * 72 + ako;
  const unsigned short* gBp[4];
  int boff[4];
#pragma unroll
  for (int p = 0; p < 4; p++) {                        // B: 64 x 64
    const int ch = t + p * 128;
    const int bn = ch >> 3, bko = (ch & 7) * 8;
    gBp[p] = Bbase + (size_t)(nG0 + bn) * K3 + bko;
    boff[p] = bn * 72 + bko;
  }

  // two named register staging sets (p = even tiles, q = odd tiles)
  u16x8 pA0, pA1, pB0, pB1, pB2, pB3;
  u16x8 qA0, qA1, qB0, qB1, qB2, qB3;

#define LOADSET(S, KT) { const int kn_ = (KT) * 64;                       \
    S##A0 = *(const u16x8*)(gA + kn_);                                    \
    S##A1 = *(const u16x8*)(gA + kn_ + 32);                               \
    S##B0 = *(const u16x8*)(gBp[0] + kn_);                                \
    S##B1 = *(const u16x8*)(gBp[1] + kn_);                                \
    S##B2 = *(const u16x8*)(gBp[2] + kn_);                                \
    S##B3 = *(const u16x8*)(gBp[3] + kn_); }

#define WRITESET(S, BUF) { unsigned short* An_ = (unsigned short*)(smem + (BUF) * 13824); \
    unsigned short* Bn_ = An_ + 2304;                                     \
    *(u16x8*)(An_ + aoff)      = S##A0;                                   \
    *(u16x8*)(An_ + aoff + 32) = S##A1;                                   \
    *(u16x8*)(Bn_ + boff[0]) = S##B0;                                     \
    *(u16x8*)(Bn_ + boff[1]) = S##B1;                                     \
    *(u16x8*)(Bn_ + boff[2]) = S##B2;                                     \
    *(u16x8*)(Bn_ + boff[3]) = S##B3; }

#define COMPUTE(BUF) { unsigned short* Ac_ = (unsigned short*)(smem + (BUF) * 13824); \
    unsigned short* Bc_ = Ac_ + 2304;                                     \
    _Pragma("unroll")                                                     \
    for (int ks2 = 0; ks2 < 2; ks2++) {                                   \
      s16x8 aW[2], bE[2];                                                 \
      _Pragma("unroll")                                                   \
      for (int f = 0; f < 2; f++) {                                       \
        aW[f] = *(const s16x8*)(Bc_ + (w * 32 + f * 16 + lr) * 72 + ks2 * 32 + klane * 8); \
        bE[f] = *(const s16x8*)(Ac_ + (f * 16 + lr) * 72 + ks2 * 32 + klane * 8);          \
      }                                                                   \
      _Pragma("unroll")                                                   \
      for (int fn = 0; fn < 2; fn++)                                      \
        _Pragma("unroll")                                                 \
        for (int fm = 0; fm < 2; fm++)                                    \
          acc[fn][fm] = __builtin_amdgcn_mfma_f32_16x16x32_bf16(          \
              aW[fn], bE[fm], acc[fn][fm], 0, 0, 0);                      \
    } }

  // prologue: tiles 0 and 1 into regs; tile 0 into LDS buf0
  LOADSET(p, 0);
  LOADSET(q, 1);
  WRITESET(p, 0);
  __syncthreads();

  for (int kt = 0; kt < 36; kt += 2) {
    // even body: compute tile kt from buf0; prefetch kt+2; stage kt+1 -> buf1
    if (kt < 34) LOADSET(p, kt + 2);
    COMPUTE(0);
    WRITESET(q, 1);
    __syncthreads();
    // odd body: compute tile kt+1 from buf1; prefetch kt+3; stage kt+2 -> buf0
    if (kt < 34) LOADSET(q, kt + 3);      // FIXED: was kt<32 (dropped tile 35)
    COMPUTE(1);
    if (kt < 34) WRITESET(p, 0);
    __syncthreads();
  }
#undef LOADSET
#undef WRITESET
#undef COMPUTE

  // ---- epilogue: transpose via LDS, store m-major (coalesced for k_head) ----
  float* Lt = (float*)smem;               // [32][68] f32
#pragma unroll
  for (int fn = 0; fn < 2; fn++)
#pragma unroll
    for (int fm = 0; fm < 2; fm++) {
      const int nl = w * 32 + fn * 16 + klane * 4;
      const int ml = fm * 16 + lr;
      *(f32x4*)(Lt + ml * 68 + nl) = acc[fn][fm];
    }
  __syncthreads();
  const int row = t >> 2, cb = (t & 3) * 16;
  float* dst = outp + (size_t)(m0 + row) * ncols + nG0 + cb;
  const float* src = Lt + row * 68 + cb;
#pragma unroll
  for (int i = 0; i < 4; i++)
    *(f32x4*)(dst + i * 4) = *(const f32x4*)(src + i * 4);
}

// ---------------------------------------------------------------------------
// K4: per entity-row epilogue, 4 waves/block (one n-quarter per wave),
// wave shfl-reduce then LDS cross-wave reduce; thread 0 does the scalar tail.
// ---------------------------------------------------------------------------
__global__ __launch_bounds__(256) void k_head(
    const float* __restrict__ Hall, const float* __restrict__ mainPart,
    const float* __restrict__ mb1, const float* __restrict__ mW2, const float* __restrict__ mb2,
    const float* __restrict__ pb1, const float* __restrict__ pW2, const float* __restrict__ pb2,
    const float* __restrict__ ab1, const float* __restrict__ aW2, const float* __restrict__ ab2,
    const float* __restrict__ ib1, const float* __restrict__ iW2, const float* __restrict__ ib2,
    float* __restrict__ out)
{
  __shared__ float red[4][25];
  const int m = blockIdx.x;
  const int t = threadIdx.x;
  const int l = t & 63, wi = t >> 6;
  const int n = t;                      // 0..255, contiguous per wave

  float h = mainPart[((size_t)0 * NE + m) * HID + n]
          + mainPart[((size_t)1 * NE + m) * HID + n]
          + mainPart[((size_t)2 * NE + m) * HID + n]
          + mb1[n];
  h = h > 0.f ? h : 0.f;
  float am0 = h * mW2[n * 3 + 0];
  float am1 = h * mW2[n * 3 + 1];
  float am2 = h * mW2[n * 3 + 2];

  float hp = Hall[(size_t)m * 768 + n] + pb1[n];
  hp = hp > 0.f ? hp : 0.f;
  float ap[6];
#pragma unroll
  for (int o = 0; o < 6; o++) ap[o] = hp * pW2[n * 6 + o];

  float ha = Hall[(size_t)m * 768 + 256 + n] + ab1[n];
  ha = ha > 0.f ? ha : 0.f;
  float aa[12];
#pragma unroll
  for (int o = 0; o < 12; o++) aa[o] = ha * aW2[n * 12 + o];

  float hv = Hall[(size_t)m * 768 + 512 + n] + ib1[n];
  hv = hv > 0.f ? hv : 0.f;
  float ai[4];
#pragma unroll
  for (int o = 0; o < 4; o++) ai[o] = hv * iW2[n * 4 + o];

#pragma unroll
  for (int d = 1; d < 64; d <<= 1) {
    am0 += __shfl_xor(am0, d);
    am1 += __shfl_xor(am1, d);
    am2 += __shfl_xor(am2, d);
#pragma unroll
    for (int o = 0; o < 6; o++)  ap[o] += __shfl_xor(ap[o], d);
#pragma unroll
    for (int o = 0; o < 12; o++) aa[o] += __shfl_xor(aa[o], d);
#pragma unroll
    for (int o = 0; o < 4; o++)  ai[o] += __shfl_xor(ai[o], d);
  }

  if (l == 0) {
    red[wi][0] = am0; red[wi][1] = am1; red[wi][2] = am2;
#pragma unroll
    for (int o = 0; o < 6; o++)  red[wi][3 + o]  = ap[o];
#pragma unroll
    for (int o = 0; o < 12; o++) red[wi][9 + o]  = aa[o];
#pragma unroll
    for (int o = 0; o < 4; o++)  red[wi][21 + o] = ai[o];
  }
  __syncthreads();

  if (t == 0) {
    float v[25];
#pragma unroll
    for (int j = 0; j < 25; j++)
      v[j] = red[0][j] + red[1][j] + red[2][j] + red[3][j];

    const float l0 = v[0] + mb2[0], l1 = v[1] + mb2[1], l2 = v[2] + mb2[2];
    const float mx = fmaxf(l0, fmaxf(l1, l2));
    const float e0 = expf(l0 - mx), e1 = expf(l1 - mx), e2 = expf(l2 - mx);
    const float inv = 1.0f / (e0 + e1 + e2);
    const float p0 = e0 * inv, p1 = e1 * inv, p2 = e2 * inv;
    int pred = 0;
    float pb = p0;
    if (p1 > pb) { pb = p1; pred = 1; }
    if (p2 > pb) { pb = p2; pred = 2; }

    out[m * 3 + 0] = l0;
    out[m * 3 + 1] = l1;
    out[m * 3 + 2] = l2;
    out[1536 + m * 3 + 0] = p0;
    out[1536 + m * 3 + 1] = p1;
    out[1536 + m * 3 + 2] = p2;

    float f[22];
#pragma unroll
    for (int j = 0; j < 22; j++) f[j] = 0.f;
    if (pred == 0) {
#pragma unroll
      for (int j = 0; j < 6; j++)  f[j]      = 1.0f / (1.0f + expf(-(v[3 + j]  + pb2[j])));
    } else if (pred == 1) {
#pragma unroll
      for (int j = 0; j < 12; j++) f[6 + j]  = 1.0f / (1.0f + expf(-(v[9 + j]  + ab2[j])));
    } else {
#pragma unroll
      for (int j = 0; j < 4; j++)  f[18 + j] = 1.0f / (1.0f + expf(-(v[21 + j] + ib2[j])));
    }
#pragma unroll
    for (int j = 0; j < 22; j++) out[3072 + m * 22 + j] = f[j];
  }
}

// ---------------------------------------------------------------------------
extern "C" void kernel_launch(void* const* d_in, const int* in_sizes, int n_in,
                              void* d_out, int out_size, void* d_ws, size_t ws_size,
                              hipStream_t stream)
{
  const float* seq    = (const float*)d_in[0];
  const int*   starts = (const int*)d_in[1];
  const int*   ends   = (const int*)d_in[2];
  const float* mW1 = (const float*)d_in[3];
  const float* mb1 = (const float*)d_in[4];
  const float* mW2 = (const float*)d_in[5];
  const float* mb2 = (const float*)d_in[6];
  const float* pW1 = (const float*)d_in[7];
  const float* pb1 = (const float*)d_in[8];
  const float* pW2 = (const float*)d_in[9];
  const float* pb2 = (const float*)d_in[10];
  const float* aW1 = (const float*)d_in[11];
  const float* ab1 = (const float*)d_in[12];
  const float* aW2 = (const float*)d_in[13];
  const float* ab2 = (const float*)d_in[14];
  const float* iW1 = (const float*)d_in[15];
  const float* ib1 = (const float*)d_in[16];
  const float* iW2 = (const float*)d_in[17];
  const float* ib2 = (const float*)d_in[18];

  char* ws = (char*)d_ws;
  float*          chunkSum = (float*)(ws);                       // 3,145,728
  float*          cap      = (float*)(ws + 3145728);             // 3,145,728
  unsigned short* embB     = (unsigned short*)(ws + 6291456);    // 2,359,296
  unsigned short* embLo    = (unsigned short*)(ws + 8650752);    // 2,359,296
  unsigned short* wT       = (unsigned short*)(ws + 11010048);   // 3,538,944
  unsigned short* wTmH     = (unsigned short*)(ws + 14548992);   // 1,179,648
  unsigned short* wTmL     = (unsigned short*)(ws + 15728640);   // 1,179,648
  float*          Hall     = (float*)(ws + 16908288);            // 512*768*4 = 1,572,864
  float*          mainPart = (float*)(ws + 18481152);            // 3*512*256*4 = 1,572,864
  // total ws use: 20,054,016 bytes

  k_scan<<<dim3(1792), dim3(192), 0, stream>>>(seq, starts, ends, pW1, aW1, iW1, mW1,
                                               chunkSum, cap, wT, wTmH, wTmL);
  k_emb<<<dim3(512), dim3(192), 0, stream>>>(chunkSum, cap, starts, ends, embB, embLo);
  k_gemm<<<dim3(384), dim3(128), 0, stream>>>(embB, embLo, wT, wTmH, wTmL, Hall, mainPart);
  k_head<<<dim3(512), dim3(256), 0, stream>>>(Hall, mainPart,
                                              mb1, mW2, mb2, pb1, pW2, pb2,
                                              ab1, aW2, ab2, ib1, iW2, ib2,
                                              (float*)d_out);
}

// Round 5
// 51.145 us; speedup vs baseline: 1.3385x; 1.0344x over previous
//
#include <hip/hip_runtime.h>

// Problem constants (B,S,H,E)=(64,512,768,8), HID=256
#define HH   768
#define SS   512
#define BB   64
#define NE   512          // B*E rows
#define K3   2304         // 3*H
#define HID  256
#define NCH  16           // chunks per batch
#define CRW  32           // rows per chunk
#define NCOL 1280         // Hall cols: p(256) a(256) i(256) mainHi(256) mainLo(256)

typedef __attribute__((ext_vector_type(4))) float  f32x4;
typedef _Float16 f16;
typedef __attribute__((ext_vector_type(8))) _Float16 f16x8;
typedef __attribute__((ext_vector_type(4))) _Float16 f16x4;

// ---------------------------------------------------------------------------
// K1: blocks 0..1023: per-(batch,chunk) partial sums over 32 rows with prefix
//     captures at event positions.
//     blocks 1024..1983: transpose+convert W1 matrices to fp16 [n][k] into
//     wT[1280][2304]: slots 0..2 = pW1/aW1/iW1, slot 3 = mW1 hi,
//     slot 4 = mW1 residual (w - (f32)(f16)w).
// ---------------------------------------------------------------------------
__global__ __launch_bounds__(192) void k_scan(
    const float* __restrict__ seq, const int* __restrict__ starts,
    const int* __restrict__ ends, const float* __restrict__ pW1,
    const float* __restrict__ aW1, const float* __restrict__ iW1,
    const float* __restrict__ mW1,
    float* __restrict__ chunkSum, float* __restrict__ cap,
    f16* __restrict__ wT)
{
  __shared__ float Ls[48 * 65];
  const int bx = blockIdx.x;
  const int t  = threadIdx.x;

  if (bx < BB * NCH) {
    // ---- scan block ----
    const int b = bx >> 4, c = bx & 15;
    int ev[16];
#pragma unroll
    for (int j = 0; j < 8; j++) {
      ev[j]     = starts[b * 8 + j];
      ev[8 + j] = ends[b * 8 + j] + 1;
    }
    unsigned rowhit = 0;
#pragma unroll
    for (int j = 0; j < 16; j++) {
      const int d = ev[j] - c * CRW;
      if ((unsigned)d < 32u) rowhit |= (1u << d);
    }
    const float* base = seq + ((size_t)(b * SS + c * CRW)) * HH + t * 4;
    f32x4 run = {0.f, 0.f, 0.f, 0.f};
#pragma unroll 8
    for (int r = 0; r < CRW; r++) {
      const int s = c * CRW + r;
      if (rowhit & (1u << r)) {        // uniform (scalar) branch, rare
#pragma unroll
        for (int j = 0; j < 16; j++) {
          if (ev[j] == s)
            *(f32x4*)(cap + ((size_t)(b * 16 + j)) * HH + t * 4) = run;
        }
      }
      f32x4 v = *(const f32x4*)(base + (size_t)r * HH);
      run += v;
    }
    *(f32x4*)(chunkSum + ((size_t)(b * 16 + c)) * HH + t * 4) = run;
  } else {
    // ---- W1 transpose/convert block: 48(k) x 64(n) tile ----
    const int bi   = bx - BB * NCH;       // 0..959
    const int slot = bi / 192;            // 0=p,1=a,2=i,3=mainHi,4=mainLo
    const int r    = bi % 192;
    const int kt = r >> 2, nt = r & 3;
    const int k0 = kt * 48, n0 = nt * 64;
    const float* W = (slot == 0) ? pW1 : ((slot == 1) ? aW1 :
                     ((slot == 2) ? iW1 : mW1));
#pragma unroll
    for (int p = 0; p < 4; p++) {
      const int row = (t >> 4) + p * 12;     // 0..47
      const int col = (t & 15) * 4;          // 0..60
      f32x4 v = *(const f32x4*)(W + (size_t)(k0 + row) * HID + n0 + col);
      Ls[row * 65 + col + 0] = v.x;
      Ls[row * 65 + col + 1] = v.y;
      Ls[row * 65 + col + 2] = v.z;
      Ls[row * 65 + col + 3] = v.w;
    }
    __syncthreads();
    const int n = t / 3, u = t % 3;          // n:0..63, u:0..2
#pragma unroll
    for (int j = 0; j < 2; j++) {
      const int kb = u * 16 + j * 8;         // 0..40 step 8
      f16x8 pk;
#pragma unroll
      for (int i = 0; i < 8; i++) {
        float x = Ls[(kb + i) * 65 + n];
        if (slot == 4) { const f16 h = (f16)x; x = x - (float)h; }
        pk[i] = (f16)x;
      }
      *(f16x8*)(wT + (size_t)(slot * 256 + n0 + n) * K3 + k0 + kb) = pk;
    }
  }
}

// ---------------------------------------------------------------------------
// K2: build emb (512 x 2304) as fp16 (embH).
// ---------------------------------------------------------------------------
__global__ __launch_bounds__(192) void k_emb(
    const float* __restrict__ chunkSum, const float* __restrict__ cap,
    const int* __restrict__ starts, const int* __restrict__ ends,
    f16* __restrict__ embH)
{
  const int bx = blockIdx.x;            // row = b*8+e
  const int t  = threadIdx.x;
  const int b = bx >> 3, e = bx & 7;
  const int s  = starts[b * 8 + e];
  const int en = ends[b * 8 + e];
  const int cs = s >> 5, ce = (en + 1) >> 5;   // both <= 15

  const float* csb = chunkSum + (size_t)(b * 16) * HH + t * 4;
  f32x4 acc = {0.f, 0.f, 0.f, 0.f};
  f32x4 baseS = {0.f, 0.f, 0.f, 0.f}, baseE = {0.f, 0.f, 0.f, 0.f};
#pragma unroll
  for (int c = 0; c < 16; c++) {
    if (c == cs) baseS = acc;
    if (c == ce) baseE = acc;
    acc += *(const f32x4*)(csb + (size_t)c * HH);
  }
  f32x4 capS = *(const f32x4*)(cap + (size_t)(b * 16 + e) * HH + t * 4);
  f32x4 capE = *(const f32x4*)(cap + (size_t)(b * 16 + 8 + e) * HH + t * 4);
  f32x4 Ps = baseS + capS;
  f32x4 Pe = baseE + capE;
  f32x4 Pt = acc;

  f32x4 zero = {0.f, 0.f, 0.f, 0.f};
  f32x4 left = zero;
  if (s > 0) left = Ps * (1.0f / (float)s);
  f32x4 span = (Pe - Ps) * (1.0f / (float)(en - s + 1));
  const int rc = SS - (en + 1);
  f32x4 right = zero;
  if (rc > 0) right = (Pt - Pe) * (1.0f / (float)rc);

  f16* ob = embH + (size_t)bx * K3 + t * 4;
  f16x4 p0, p1, p2;
#pragma unroll
  for (int i = 0; i < 4; i++) {
    p0[i] = (f16)left[i];
    p1[i] = (f16)span[i];
    p2[i] = (f16)right[i];
  }
  *(f16x4*)(ob)        = p0;
  *(f16x4*)(ob + 768)  = p1;
  *(f16x4*)(ob + 1536) = p2;
}

// ---------------------------------------------------------------------------
// K3: unified fp16 MFMA GEMM: Hall[512 m][1280 n] = embH (512x2304) x
//     wT^T (1280x2304), 32x64 tiles, grid 16mt x 20nt = 320 blocks.
// 4 waves: wave w -> (n-half w&1, K-half kw=w>>1 of each 64-wide tile).
// 2-deep modulo-scheduled pipeline (verified R4 skeleton, guards kt<34):
// load T(kt+2)->regs, compute T(kt) from LDS, ds_write T(kt+1).
// Epilogue: cross-wave K-half reduce + transpose via LDS, m-major store.
// ---------------------------------------------------------------------------
__global__ __launch_bounds__(256) void k_gemm(
    const f16* __restrict__ embH, const f16* __restrict__ wT,
    float* __restrict__ Hall)
{
  __shared__ __align__(16) char smem[27648];   // 2 x (A 32x72 + B 64x72) fp16
  const int bx = blockIdx.x;
  const int t  = threadIdx.x;
  const int mt = bx & 15, nt = bx >> 4;        // nt 0..19
  const int m0 = mt * 32, nG0 = nt * 64;

  const int l = t & 63, w = t >> 6;       // 4 waves
  const int w2 = w & 1;                   // n-half
  const int kw = w >> 1;                  // K-half of each 64-tile
  const int klane = l >> 4;               // 0..3
  const int lr = l & 15;
  f32x4 acc[2][2] = {};

  // staging addresses (constant per thread; k advances by immediate)
  const int am = t >> 3, ako = (t & 7) * 8;            // A: 32 x 64, 1 chunk/thread
  const f16* gA = embH + (size_t)(m0 + am) * K3 + ako;
  const int aoff = am * 72 + ako;
  const int bn0 = t >> 3,        bko0 = (t & 7) * 8;   // B: 64 x 64, 2 chunks/thread
  const int bn1 = (t + 256) >> 3, bko1 = (t & 7) * 8;
  const f16* gB0 = wT + (size_t)(nG0 + bn0) * K3 + bko0;
  const f16* gB1 = wT + (size_t)(nG0 + bn1) * K3 + bko1;
  const int boff0 = bn0 * 72 + bko0, boff1 = bn1 * 72 + bko1;

  // two named register staging sets (p = even tiles, q = odd tiles)
  f16x8 pA, pB0, pB1, qA, qB0, qB1;

#define LOADSET(S, KT) { const int kn_ = (KT) * 64;                       \
    S##A  = *(const f16x8*)(gA  + kn_);                                   \
    S##B0 = *(const f16x8*)(gB0 + kn_);                                   \
    S##B1 = *(const f16x8*)(gB1 + kn_); }

#define WRITESET(S, BUF) { f16* An_ = (f16*)(smem + (BUF) * 13824);       \
    f16* Bn_ = An_ + 2304;                                                \
    *(f16x8*)(An_ + aoff)  = S##A;                                        \
    *(f16x8*)(Bn_ + boff0) = S##B0;                                       \
    *(f16x8*)(Bn_ + boff1) = S##B1; }

#define COMPUTE(BUF) { f16* Ac_ = (f16*)(smem + (BUF) * 13824);           \
    f16* Bc_ = Ac_ + 2304;                                                \
    const int koff_ = kw * 32 + klane * 8;                                \
    f16x8 aW[2], bE[2];                                                   \
    _Pragma("unroll")                                                     \
    for (int f = 0; f < 2; f++) {                                         \
      aW[f] = *(const f16x8*)(Bc_ + (w2 * 32 + f * 16 + lr) * 72 + koff_);\
      bE[f] = *(const f16x8*)(Ac_ + (f * 16 + lr) * 72 + koff_);          \
    }                                                                     \
    _Pragma("unroll")                                                     \
    for (int fn = 0; fn < 2; fn++)                                        \
      _Pragma("unroll")                                                   \
      for (int fm = 0; fm < 2; fm++)                                      \
        acc[fn][fm] = __builtin_amdgcn_mfma_f32_16x16x32_f16(             \
            aW[fn], bE[fm], acc[fn][fm], 0, 0, 0); }

  // prologue: tiles 0 and 1 into regs; tile 0 into LDS buf0
  LOADSET(p, 0);
  LOADSET(q, 1);
  WRITESET(p, 0);
  __syncthreads();

  for (int kt = 0; kt < 36; kt += 2) {
    // even body: compute tile kt from buf0; prefetch kt+2; stage kt+1 -> buf1
    if (kt < 34) LOADSET(p, kt + 2);
    COMPUTE(0);
    WRITESET(q, 1);
    __syncthreads();
    // odd body: compute tile kt+1 from buf1; prefetch kt+3; stage kt+2 -> buf0
    if (kt < 34) LOADSET(q, kt + 3);
    COMPUTE(1);
    if (kt < 34) WRITESET(p, 0);
    __syncthreads();
  }
#undef LOADSET
#undef WRITESET
#undef COMPUTE

  // ---- epilogue: K-half reduce across wave pairs + transpose via LDS ----
  float* Lt = (float*)smem;               // [32][68] f32
  if (kw == 1) {
#pragma unroll
    for (int fn = 0; fn < 2; fn++)
#pragma unroll
      for (int fm = 0; fm < 2; fm++) {
        const int nl = w2 * 32 + fn * 16 + klane * 4;
        const int ml = fm * 16 + lr;
        *(f32x4*)(Lt + ml * 68 + nl) = acc[fn][fm];
      }
  }
  __syncthreads();
  if (kw == 0) {
#pragma unroll
    for (int fn = 0; fn < 2; fn++)
#pragma unroll
      for (int fm = 0; fm < 2; fm++) {
        const int nl = w2 * 32 + fn * 16 + klane * 4;
        const int ml = fm * 16 + lr;
        f32x4* pd = (f32x4*)(Lt + ml * 68 + nl);
        *pd = *pd + acc[fn][fm];
      }
  }
  __syncthreads();
  const int row = t >> 3, cb = (t & 7) * 8;   // 32 rows x 8 col-chunks
  float* dst = Hall + (size_t)(m0 + row) * NCOL + nG0 + cb;
  const float* src = Lt + row * 68 + cb;
  *(f32x4*)(dst)     = *(const f32x4*)(src);
  *(f32x4*)(dst + 4) = *(const f32x4*)(src + 4);
}

// ---------------------------------------------------------------------------
// K4: per entity-row epilogue, 4 waves/block (one n per thread), wave
// shfl-reduce then LDS cross-wave reduce; thread 0 does the scalar tail.
// ---------------------------------------------------------------------------
__global__ __launch_bounds__(256) void k_head(
    const float* __restrict__ Hall,
    const float* __restrict__ mb1, const float* __restrict__ mW2, const float* __restrict__ mb2,
    const float* __restrict__ pb1, const float* __restrict__ pW2, const float* __restrict__ pb2,
    const float* __restrict__ ab1, const float* __restrict__ aW2, const float* __restrict__ ab2,
    const float* __restrict__ ib1, const float* __restrict__ iW2, const float* __restrict__ ib2,
    float* __restrict__ out)
{
  __shared__ float red[4][25];
  const int m = blockIdx.x;
  const int t = threadIdx.x;
  const int l = t & 63, wi = t >> 6;
  const int n = t;                      // 0..255
  const float* hrow = Hall + (size_t)m * NCOL;

  float h = hrow[768 + n] + hrow[1024 + n] + mb1[n];   // mainHi + mainLo
  h = h > 0.f ? h : 0.f;
  float am0 = h * mW2[n * 3 + 0];
  float am1 = h * mW2[n * 3 + 1];
  float am2 = h * mW2[n * 3 + 2];

  float hp = hrow[n] + pb1[n];
  hp = hp > 0.f ? hp : 0.f;
  float ap[6];
#pragma unroll
  for (int o = 0; o < 6; o++) ap[o] = hp * pW2[n * 6 + o];

  float ha = hrow[256 + n] + ab1[n];
  ha = ha > 0.f ? ha : 0.f;
  float aa[12];
#pragma unroll
  for (int o = 0; o < 12; o++) aa[o] = ha * aW2[n * 12 + o];

  float hv = hrow[512 + n] + ib1[n];
  hv = hv > 0.f ? hv : 0.f;
  float ai[4];
#pragma unroll
  for (int o = 0; o < 4; o++) ai[o] = hv * iW2[n * 4 + o];

#pragma unroll
  for (int d = 1; d < 64; d <<= 1) {
    am0 += __shfl_xor(am0, d);
    am1 += __shfl_xor(am1, d);
    am2 += __shfl_xor(am2, d);
#pragma unroll
    for (int o = 0; o < 6; o++)  ap[o] += __shfl_xor(ap[o], d);
#pragma unroll
    for (int o = 0; o < 12; o++) aa[o] += __shfl_xor(aa[o], d);
#pragma unroll
    for (int o = 0; o < 4; o++)  ai[o] += __shfl_xor(ai[o], d);
  }

  if (l == 0) {
    red[wi][0] = am0; red[wi][1] = am1; red[wi][2] = am2;
#pragma unroll
    for (int o = 0; o < 6; o++)  red[wi][3 + o]  = ap[o];
#pragma unroll
    for (int o = 0; o < 12; o++) red[wi][9 + o]  = aa[o];
#pragma unroll
    for (int o = 0; o < 4; o++)  red[wi][21 + o] = ai[o];
  }
  __syncthreads();

  if (t == 0) {
    float v[25];
#pragma unroll
    for (int j = 0; j < 25; j++)
      v[j] = red[0][j] + red[1][j] + red[2][j] + red[3][j];

    const float l0 = v[0] + mb2[0], l1 = v[1] + mb2[1], l2 = v[2] + mb2[2];
    const float mx = fmaxf(l0, fmaxf(l1, l2));
    const float e0 = expf(l0 - mx), e1 = expf(l1 - mx), e2 = expf(l2 - mx);
    const float inv = 1.0f / (e0 + e1 + e2);
    const float p0 = e0 * inv, p1 = e1 * inv, p2 = e2 * inv;
    int pred = 0;
    float pb = p0;
    if (p1 > pb) { pb = p1; pred = 1; }
    if (p2 > pb) { pb = p2; pred = 2; }

    out[m * 3 + 0] = l0;
    out[m * 3 + 1] = l1;
    out[m * 3 + 2] = l2;
    out[1536 + m * 3 + 0] = p0;
    out[1536 + m * 3 + 1] = p1;
    out[1536 + m * 3 + 2] = p2;

    float f[22];
#pragma unroll
    for (int j = 0; j < 22; j++) f[j] = 0.f;
    if (pred == 0) {
#pragma unroll
      for (int j = 0; j < 6; j++)  f[j]      = 1.0f / (1.0f + expf(-(v[3 + j]  + pb2[j])));
    } else if (pred == 1) {
#pragma unroll
      for (int j = 0; j < 12; j++) f[6 + j]  = 1.0f / (1.0f + expf(-(v[9 + j]  + ab2[j])));
    } else {
#pragma unroll
      for (int j = 0; j < 4; j++)  f[18 + j] = 1.0f / (1.0f + expf(-(v[21 + j] + ib2[j])));
    }
#pragma unroll
    for (int j = 0; j < 22; j++) out[3072 + m * 22 + j] = f[j];
  }
}

// ---------------------------------------------------------------------------
extern "C" void kernel_launch(void* const* d_in, const int* in_sizes, int n_in,
                              void* d_out, int out_size, void* d_ws, size_t ws_size,
                              hipStream_t stream)
{
  const float* seq    = (const float*)d_in[0];
  const int*   starts = (const int*)d_in[1];
  const int*   ends   = (const int*)d_in[2];
  const float* mW1 = (const float*)d_in[3];
  const float* mb1 = (const float*)d_in[4];
  const float* mW2 = (const float*)d_in[5];
  const float* mb2 = (const float*)d_in[6];
  const float* pW1 = (const float*)d_in[7];
  const float* pb1 = (const float*)d_in[8];
  const float* pW2 = (const float*)d_in[9];
  const float* pb2 = (const float*)d_in[10];
  const float* aW1 = (const float*)d_in[11];
  const float* ab1 = (const float*)d_in[12];
  const float* aW2 = (const float*)d_in[13];
  const float* ab2 = (const float*)d_in[14];
  const float* iW1 = (const float*)d_in[15];
  const float* ib1 = (const float*)d_in[16];
  const float* iW2 = (const float*)d_in[17];
  const float* ib2 = (const float*)d_in[18];

  char* ws = (char*)d_ws;
  float* chunkSum = (float*)(ws);                  // 3,145,728
  float* cap      = (float*)(ws + 3145728);        // 3,145,728
  f16*   embH     = (f16*)(ws + 6291456);          // 512*2304*2  = 2,359,296
  f16*   wT       = (f16*)(ws + 8650752);          // 1280*2304*2 = 5,898,240
  float* Hall     = (float*)(ws + 14548992);       // 512*1280*4  = 2,621,440
  // total ws use: 17,170,432 bytes

  k_scan<<<dim3(1984), dim3(192), 0, stream>>>(seq, starts, ends, pW1, aW1, iW1, mW1,
                                               chunkSum, cap, wT);
  k_emb<<<dim3(512), dim3(192), 0, stream>>>(chunkSum, cap, starts, ends, embH);
  k_gemm<<<dim3(320), dim3(256), 0, stream>>>(embH, wT, Hall);
  k_head<<<dim3(512), dim3(256), 0, stream>>>(Hall,
                                              mb1, mW2, mb2, pb1, pW2, pb2,
                                              ab1, aW2, ab2, ib1, iW2, ib2,
                                              (float*)d_out);
}

// Round 6
// 49.613 us; speedup vs baseline: 1.3798x; 1.0309x over previous
//
#include <hip/hip_runtime.h>

// Problem constants (B,S,H,E)=(64,512,768,8), HID=256
#define HH   768
#define SS   512
#define BB   64
#define NE   512          // B*E rows
#define K3   2304         // 3*H
#define HID  256
#define NCH  16           // chunks per batch
#define CRW  32           // rows per chunk
#define NCOL 1280         // Hall cols: p(256) a(256) i(256) mainHi(256) mainLo(256)

typedef __attribute__((ext_vector_type(4))) float  f32x4;
typedef _Float16 f16;
typedef __attribute__((ext_vector_type(8))) _Float16 f16x8;
typedef __attribute__((ext_vector_type(4))) _Float16 f16x4;

// ---------------------------------------------------------------------------
// K1: blocks 0..1023: per-(batch,chunk) partial sums over 32 rows with prefix
//     captures at event positions.
//     blocks 1024..1983: transpose+convert W1 matrices to fp16 [n][k] into
//     wT[1280][2304]: slots 0..2 = pW1/aW1/iW1, slot 3 = mW1 hi,
//     slot 4 = mW1 residual (w - (f32)(f16)w).
// ---------------------------------------------------------------------------
__global__ __launch_bounds__(192) void k_scan(
    const float* __restrict__ seq, const int* __restrict__ starts,
    const int* __restrict__ ends, const float* __restrict__ pW1,
    const float* __restrict__ aW1, const float* __restrict__ iW1,
    const float* __restrict__ mW1,
    float* __restrict__ chunkSum, float* __restrict__ cap,
    f16* __restrict__ wT)
{
  __shared__ float Ls[48 * 65];
  const int bx = blockIdx.x;
  const int t  = threadIdx.x;

  if (bx < BB * NCH) {
    // ---- scan block ----
    const int b = bx >> 4, c = bx & 15;
    int ev[16];
#pragma unroll
    for (int j = 0; j < 8; j++) {
      ev[j]     = starts[b * 8 + j];
      ev[8 + j] = ends[b * 8 + j] + 1;
    }
    unsigned rowhit = 0;
#pragma unroll
    for (int j = 0; j < 16; j++) {
      const int d = ev[j] - c * CRW;
      if ((unsigned)d < 32u) rowhit |= (1u << d);
    }
    const float* base = seq + ((size_t)(b * SS + c * CRW)) * HH + t * 4;
    f32x4 run = {0.f, 0.f, 0.f, 0.f};
#pragma unroll 8
    for (int r = 0; r < CRW; r++) {
      const int s = c * CRW + r;
      if (rowhit & (1u << r)) {        // uniform (scalar) branch, rare
#pragma unroll
        for (int j = 0; j < 16; j++) {
          if (ev[j] == s)
            *(f32x4*)(cap + ((size_t)(b * 16 + j)) * HH + t * 4) = run;
        }
      }
      f32x4 v = *(const f32x4*)(base + (size_t)r * HH);
      run += v;
    }
    *(f32x4*)(chunkSum + ((size_t)(b * 16 + c)) * HH + t * 4) = run;
  } else {
    // ---- W1 transpose/convert block: 48(k) x 64(n) tile ----
    const int bi   = bx - BB * NCH;       // 0..959
    const int slot = bi / 192;            // 0=p,1=a,2=i,3=mainHi,4=mainLo
    const int r    = bi % 192;
    const int kt = r >> 2, nt = r & 3;
    const int k0 = kt * 48, n0 = nt * 64;
    const float* W = (slot == 0) ? pW1 : ((slot == 1) ? aW1 :
                     ((slot == 2) ? iW1 : mW1));
#pragma unroll
    for (int p = 0; p < 4; p++) {
      const int row = (t >> 4) + p * 12;     // 0..47
      const int col = (t & 15) * 4;          // 0..60
      f32x4 v = *(const f32x4*)(W + (size_t)(k0 + row) * HID + n0 + col);
      Ls[row * 65 + col + 0] = v.x;
      Ls[row * 65 + col + 1] = v.y;
      Ls[row * 65 + col + 2] = v.z;
      Ls[row * 65 + col + 3] = v.w;
    }
    __syncthreads();
    const int n = t / 3, u = t % 3;          // n:0..63, u:0..2
#pragma unroll
    for (int j = 0; j < 2; j++) {
      const int kb = u * 16 + j * 8;         // 0..40 step 8
      f16x8 pk;
#pragma unroll
      for (int i = 0; i < 8; i++) {
        float x = Ls[(kb + i) * 65 + n];
        if (slot == 4) { const f16 h = (f16)x; x = x - (float)h; }
        pk[i] = (f16)x;
      }
      *(f16x8*)(wT + (size_t)(slot * 256 + n0 + n) * K3 + k0 + kb) = pk;
    }
  }
}

// ---------------------------------------------------------------------------
// K2: build emb (512 x 2304) as fp16 (embH).
// ---------------------------------------------------------------------------
__global__ __launch_bounds__(192) void k_emb(
    const float* __restrict__ chunkSum, const float* __restrict__ cap,
    const int* __restrict__ starts, const int* __restrict__ ends,
    f16* __restrict__ embH)
{
  const int bx = blockIdx.x;            // row = b*8+e
  const int t  = threadIdx.x;
  const int b = bx >> 3, e = bx & 7;
  const int s  = starts[b * 8 + e];
  const int en = ends[b * 8 + e];
  const int cs = s >> 5, ce = (en + 1) >> 5;   // both <= 15

  const float* csb = chunkSum + (size_t)(b * 16) * HH + t * 4;
  f32x4 acc = {0.f, 0.f, 0.f, 0.f};
  f32x4 baseS = {0.f, 0.f, 0.f, 0.f}, baseE = {0.f, 0.f, 0.f, 0.f};
#pragma unroll
  for (int c = 0; c < 16; c++) {
    if (c == cs) baseS = acc;
    if (c == ce) baseE = acc;
    acc += *(const f32x4*)(csb + (size_t)c * HH);
  }
  f32x4 capS = *(const f32x4*)(cap + (size_t)(b * 16 + e) * HH + t * 4);
  f32x4 capE = *(const f32x4*)(cap + (size_t)(b * 16 + 8 + e) * HH + t * 4);
  f32x4 Ps = baseS + capS;
  f32x4 Pe = baseE + capE;
  f32x4 Pt = acc;

  f32x4 zero = {0.f, 0.f, 0.f, 0.f};
  f32x4 left = zero;
  if (s > 0) left = Ps * (1.0f / (float)s);
  f32x4 span = (Pe - Ps) * (1.0f / (float)(en - s + 1));
  const int rc = SS - (en + 1);
  f32x4 right = zero;
  if (rc > 0) right = (Pt - Pe) * (1.0f / (float)rc);

  f16* ob = embH + (size_t)bx * K3 + t * 4;
  f16x4 p0, p1, p2;
#pragma unroll
  for (int i = 0; i < 4; i++) {
    p0[i] = (f16)left[i];
    p1[i] = (f16)span[i];
    p2[i] = (f16)right[i];
  }
  *(f16x4*)(ob)        = p0;
  *(f16x4*)(ob + 768)  = p1;
  *(f16x4*)(ob + 1536) = p2;
}

// ---------------------------------------------------------------------------
// K3: unified fp16 MFMA GEMM: Hall[512 m][1280 n] = embH (512x2304) x
//     wT^T (1280x2304), 32x64 tiles, grid 16mt x 20nt = 320 blocks.
// XCD-chunked bijective swizzle (320%8==0): each XCD owns 40 consecutive
// work-ids = 2.5 contiguous B strips -> B becomes XCD-L2-resident (was 8x
// duplicated across XCDs with the unswizzled mt%8 mapping).
// 4 waves: wave w -> (n-half w&1, K-half kw=w>>1 of each 64-wide tile).
// 2-deep modulo-scheduled pipeline (verified R4 skeleton, guards kt<34).
// ---------------------------------------------------------------------------
__global__ __launch_bounds__(256) void k_gemm(
    const f16* __restrict__ embH, const f16* __restrict__ wT,
    float* __restrict__ Hall)
{
  __shared__ __align__(16) char smem[27648];   // 2 x (A 32x72 + B 64x72) fp16
  const int bx0 = blockIdx.x;
  const int bx  = (bx0 & 7) * 40 + (bx0 >> 3);  // XCD-chunked swizzle (bijective)
  const int t  = threadIdx.x;
  const int mt = bx & 15, nt = bx >> 4;        // nt 0..19
  const int m0 = mt * 32, nG0 = nt * 64;

  const int l = t & 63, w = t >> 6;       // 4 waves
  const int w2 = w & 1;                   // n-half
  const int kw = w >> 1;                  // K-half of each 64-tile
  const int klane = l >> 4;               // 0..3
  const int lr = l & 15;
  f32x4 acc[2][2] = {};

  // staging addresses (constant per thread; k advances by immediate)
  const int am = t >> 3, ako = (t & 7) * 8;            // A: 32 x 64, 1 chunk/thread
  const f16* gA = embH + (size_t)(m0 + am) * K3 + ako;
  const int aoff = am * 72 + ako;
  const int bn0 = t >> 3,        bko0 = (t & 7) * 8;   // B: 64 x 64, 2 chunks/thread
  const int bn1 = (t + 256) >> 3, bko1 = (t & 7) * 8;
  const f16* gB0 = wT + (size_t)(nG0 + bn0) * K3 + bko0;
  const f16* gB1 = wT + (size_t)(nG0 + bn1) * K3 + bko1;
  const int boff0 = bn0 * 72 + bko0, boff1 = bn1 * 72 + bko1;

  // two named register staging sets (p = even tiles, q = odd tiles)
  f16x8 pA, pB0, pB1, qA, qB0, qB1;

#define LOADSET(S, KT) { const int kn_ = (KT) * 64;                       \
    S##A  = *(const f16x8*)(gA  + kn_);                                   \
    S##B0 = *(const f16x8*)(gB0 + kn_);                                   \
    S##B1 = *(const f16x8*)(gB1 + kn_); }

#define WRITESET(S, BUF) { f16* An_ = (f16*)(smem + (BUF) * 13824);       \
    f16* Bn_ = An_ + 2304;                                                \
    *(f16x8*)(An_ + aoff)  = S##A;                                        \
    *(f16x8*)(Bn_ + boff0) = S##B0;                                       \
    *(f16x8*)(Bn_ + boff1) = S##B1; }

#define COMPUTE(BUF) { f16* Ac_ = (f16*)(smem + (BUF) * 13824);           \
    f16* Bc_ = Ac_ + 2304;                                                \
    const int koff_ = kw * 32 + klane * 8;                                \
    f16x8 aW[2], bE[2];                                                   \
    _Pragma("unroll")                                                     \
    for (int f = 0; f < 2; f++) {                                         \
      aW[f] = *(const f16x8*)(Bc_ + (w2 * 32 + f * 16 + lr) * 72 + koff_);\
      bE[f] = *(const f16x8*)(Ac_ + (f * 16 + lr) * 72 + koff_);          \
    }                                                                     \
    _Pragma("unroll")                                                     \
    for (int fn = 0; fn < 2; fn++)                                        \
      _Pragma("unroll")                                                   \
      for (int fm = 0; fm < 2; fm++)                                      \
        acc[fn][fm] = __builtin_amdgcn_mfma_f32_16x16x32_f16(             \
            aW[fn], bE[fm], acc[fn][fm], 0, 0, 0); }

  // prologue: tiles 0 and 1 into regs; tile 0 into LDS buf0
  LOADSET(p, 0);
  LOADSET(q, 1);
  WRITESET(p, 0);
  __syncthreads();

  for (int kt = 0; kt < 36; kt += 2) {
    // even body: compute tile kt from buf0; prefetch kt+2; stage kt+1 -> buf1
    if (kt < 34) LOADSET(p, kt + 2);
    COMPUTE(0);
    WRITESET(q, 1);
    __syncthreads();
    // odd body: compute tile kt+1 from buf1; prefetch kt+3; stage kt+2 -> buf0
    if (kt < 34) LOADSET(q, kt + 3);
    COMPUTE(1);
    if (kt < 34) WRITESET(p, 0);
    __syncthreads();
  }
#undef LOADSET
#undef WRITESET
#undef COMPUTE

  // ---- epilogue: K-half reduce across wave pairs + transpose via LDS ----
  float* Lt = (float*)smem;               // [32][68] f32
  if (kw == 1) {
#pragma unroll
    for (int fn = 0; fn < 2; fn++)
#pragma unroll
      for (int fm = 0; fm < 2; fm++) {
        const int nl = w2 * 32 + fn * 16 + klane * 4;
        const int ml = fm * 16 + lr;
        *(f32x4*)(Lt + ml * 68 + nl) = acc[fn][fm];
      }
  }
  __syncthreads();
  if (kw == 0) {
#pragma unroll
    for (int fn = 0; fn < 2; fn++)
#pragma unroll
      for (int fm = 0; fm < 2; fm++) {
        const int nl = w2 * 32 + fn * 16 + klane * 4;
        const int ml = fm * 16 + lr;
        f32x4* pd = (f32x4*)(Lt + ml * 68 + nl);
        *pd = *pd + acc[fn][fm];
      }
  }
  __syncthreads();
  const int row = t >> 3, cb = (t & 7) * 8;   // 32 rows x 8 col-chunks
  float* dst = Hall + (size_t)(m0 + row) * NCOL + nG0 + cb;
  const float* src = Lt + row * 68 + cb;
  *(f32x4*)(dst)     = *(const f32x4*)(src);
  *(f32x4*)(dst + 4) = *(const f32x4*)(src + 4);
}

// ---------------------------------------------------------------------------
// K4: per entity-row epilogue, 4 waves/block.  Reduce the 3 main logits
// first, broadcast pred (block-uniform), then reduce ONLY the selected fine
// head (6/12/4 values) — saves ~60% of the shuffle-reduce work.
// ---------------------------------------------------------------------------
__global__ __launch_bounds__(256) void k_head(
    const float* __restrict__ Hall,
    const float* __restrict__ mb1, const float* __restrict__ mW2, const float* __restrict__ mb2,
    const float* __restrict__ pb1, const float* __restrict__ pW2, const float* __restrict__ pb2,
    const float* __restrict__ ab1, const float* __restrict__ aW2, const float* __restrict__ ab2,
    const float* __restrict__ ib1, const float* __restrict__ iW2, const float* __restrict__ ib2,
    float* __restrict__ out)
{
  __shared__ float red[4][15];
  const int m = blockIdx.x;
  const int t = threadIdx.x;
  const int l = t & 63, wi = t >> 6;
  const int n = t;                      // 0..255
  const float* hrow = Hall + (size_t)m * NCOL;

  float h = hrow[768 + n] + hrow[1024 + n] + mb1[n];   // mainHi + mainLo
  h = h > 0.f ? h : 0.f;
  float am0 = h * mW2[n * 3 + 0];
  float am1 = h * mW2[n * 3 + 1];
  float am2 = h * mW2[n * 3 + 2];

  float hp = hrow[n] + pb1[n];
  hp = hp > 0.f ? hp : 0.f;
  float ha = hrow[256 + n] + ab1[n];
  ha = ha > 0.f ? ha : 0.f;
  float hv = hrow[512 + n] + ib1[n];
  hv = hv > 0.f ? hv : 0.f;

  // ---- main-head reduce first ----
#pragma unroll
  for (int d = 1; d < 64; d <<= 1) {
    am0 += __shfl_xor(am0, d);
    am1 += __shfl_xor(am1, d);
    am2 += __shfl_xor(am2, d);
  }
  if (l == 0) { red[wi][0] = am0; red[wi][1] = am1; red[wi][2] = am2; }
  __syncthreads();

  const float l0 = red[0][0] + red[1][0] + red[2][0] + red[3][0] + mb2[0];
  const float l1 = red[0][1] + red[1][1] + red[2][1] + red[3][1] + mb2[1];
  const float l2 = red[0][2] + red[1][2] + red[2][2] + red[3][2] + mb2[2];
  int pred = 0;
  {
    float pbv = l0;
    if (l1 > pbv) { pbv = l1; pred = 1; }
    if (l2 > pbv) { pbv = l2; pred = 2; }
  }

  // ---- selective fine-head reduce (pred is block-uniform) ----
  if (pred == 0) {
    float ap[6];
#pragma unroll
    for (int o = 0; o < 6; o++) ap[o] = hp * pW2[n * 6 + o];
#pragma unroll
    for (int d = 1; d < 64; d <<= 1)
#pragma unroll
      for (int o = 0; o < 6; o++) ap[o] += __shfl_xor(ap[o], d);
    if (l == 0)
#pragma unroll
      for (int o = 0; o < 6; o++) red[wi][3 + o] = ap[o];
  } else if (pred == 1) {
    float aa[12];
#pragma unroll
    for (int o = 0; o < 12; o++) aa[o] = ha * aW2[n * 12 + o];
#pragma unroll
    for (int d = 1; d < 64; d <<= 1)
#pragma unroll
      for (int o = 0; o < 12; o++) aa[o] += __shfl_xor(aa[o], d);
    if (l == 0)
#pragma unroll
      for (int o = 0; o < 12; o++) red[wi][3 + o] = aa[o];
  } else {
    float ai[4];
#pragma unroll
    for (int o = 0; o < 4; o++) ai[o] = hv * iW2[n * 4 + o];
#pragma unroll
    for (int d = 1; d < 64; d <<= 1)
#pragma unroll
      for (int o = 0; o < 4; o++) ai[o] += __shfl_xor(ai[o], d);
    if (l == 0)
#pragma unroll
      for (int o = 0; o < 4; o++) red[wi][3 + o] = ai[o];
  }
  __syncthreads();

  if (t == 0) {
    const float mx = fmaxf(l0, fmaxf(l1, l2));
    const float e0 = expf(l0 - mx), e1 = expf(l1 - mx), e2 = expf(l2 - mx);
    const float inv = 1.0f / (e0 + e1 + e2);
    const float p0 = e0 * inv, p1 = e1 * inv, p2 = e2 * inv;

    out[m * 3 + 0] = l0;
    out[m * 3 + 1] = l1;
    out[m * 3 + 2] = l2;
    out[1536 + m * 3 + 0] = p0;
    out[1536 + m * 3 + 1] = p1;
    out[1536 + m * 3 + 2] = p2;

    float f[22];
#pragma unroll
    for (int j = 0; j < 22; j++) f[j] = 0.f;
    if (pred == 0) {
#pragma unroll
      for (int j = 0; j < 6; j++) {
        const float v = red[0][3 + j] + red[1][3 + j] + red[2][3 + j] + red[3][3 + j];
        f[j] = 1.0f / (1.0f + expf(-(v + pb2[j])));
      }
    } else if (pred == 1) {
#pragma unroll
      for (int j = 0; j < 12; j++) {
        const float v = red[0][3 + j] + red[1][3 + j] + red[2][3 + j] + red[3][3 + j];
        f[6 + j] = 1.0f / (1.0f + expf(-(v + ab2[j])));
      }
    } else {
#pragma unroll
      for (int j = 0; j < 4; j++) {
        const float v = red[0][3 + j] + red[1][3 + j] + red[2][3 + j] + red[3][3 + j];
        f[18 + j] = 1.0f / (1.0f + expf(-(v + ib2[j])));
      }
    }
#pragma unroll
    for (int j = 0; j < 22; j++) out[3072 + m * 22 + j] = f[j];
  }
}

// ---------------------------------------------------------------------------
extern "C" void kernel_launch(void* const* d_in, const int* in_sizes, int n_in,
                              void* d_out, int out_size, void* d_ws, size_t ws_size,
                              hipStream_t stream)
{
  const float* seq    = (const float*)d_in[0];
  const int*   starts = (const int*)d_in[1];
  const int*   ends   = (const int*)d_in[2];
  const float* mW1 = (const float*)d_in[3];
  const float* mb1 = (const float*)d_in[4];
  const float* mW2 = (const float*)d_in[5];
  const float* mb2 = (const float*)d_in[6];
  const float* pW1 = (const float*)d_in[7];
  const float* pb1 = (const float*)d_in[8];
  const float* pW2 = (const float*)d_in[9];
  const float* pb2 = (const float*)d_in[10];
  const float* aW1 = (const float*)d_in[11];
  const float* ab1 = (const float*)d_in[12];
  const float* aW2 = (const float*)d_in[13];
  const float* ab2 = (const float*)d_in[14];
  const float* iW1 = (const float*)d_in[15];
  const float* ib1 = (const float*)d_in[16];
  const float* iW2 = (const float*)d_in[17];
  const float* ib2 = (const float*)d_in[18];

  char* ws = (char*)d_ws;
  float* chunkSum = (float*)(ws);                  // 3,145,728
  float* cap      = (float*)(ws + 3145728);        // 3,145,728
  f16*   embH     = (f16*)(ws + 6291456);          // 512*2304*2  = 2,359,296
  f16*   wT       = (f16*)(ws + 8650752);          // 1280*2304*2 = 5,898,240
  float* Hall     = (float*)(ws + 14548992);       // 512*1280*4  = 2,621,440
  // total ws use: 17,170,432 bytes

  k_scan<<<dim3(1984), dim3(192), 0, stream>>>(seq, starts, ends, pW1, aW1, iW1, mW1,
                                               chunkSum, cap, wT);
  k_emb<<<dim3(512), dim3(192), 0, stream>>>(chunkSum, cap, starts, ends, embH);
  k_gemm<<<dim3(320), dim3(256), 0, stream>>>(embH, wT, Hall);
  k_head<<<dim3(512), dim3(256), 0, stream>>>(Hall,
                                              mb1, mW2, mb2, pb1, pW2, pb2,
                                              ab1, aW2, ab2, ib1, iW2, ib2,
                                              (float*)d_out);
}